// Round 6
// baseline (3688.902 us; speedup 1.0000x reference)
//
#include <hip/hip_runtime.h>

typedef unsigned short u16;
typedef unsigned int u32;
typedef __bf16 bf16x8 __attribute__((ext_vector_type(8)));
typedef float f32x4 __attribute__((ext_vector_type(4)));

#define HIDDEN 2048
#define SEQ 4096
#define HEADS 8
#define HD 256

__device__ __forceinline__ u16 f2bf(float f) {
  u32 u = __float_as_uint(f);
  u32 r = (u + 0x7fffu + ((u >> 16) & 1u)) >> 16;
  return (u16)r;
}
__device__ __forceinline__ float bf2f(u16 h) {
  return __uint_as_float(((u32)h) << 16);
}
__device__ __forceinline__ void async16(void* lds, const void* g) {
  __builtin_amdgcn_global_load_lds(
      (__attribute__((address_space(1))) void*)g,
      (__attribute__((address_space(3))) void*)lds, 16, 0, 0);
}

// ---------------- convert x to bf16 ----------------
__global__ __launch_bounds__(256) void k_cvt_x(const float* __restrict__ x,
                                               u16* __restrict__ xb) {
  int i = blockIdx.x * 256 + threadIdx.x;
  float4 v = ((const float4*)x)[i];
  ushort4 o;
  o.x = f2bf(v.x); o.y = f2bf(v.y); o.z = f2bf(v.z); o.w = f2bf(v.w);
  ((ushort4*)xb)[i] = o;
}

// ---------------- transpose weights to bf16 W^T[c][k] ----------------
__global__ __launch_bounds__(256) void k_transpose(
    const float* __restrict__ w0, const float* __restrict__ w1,
    const float* __restrict__ w2, const float* __restrict__ w3,
    const float* __restrict__ w4, u16* __restrict__ dst) {
  const float* src = (blockIdx.z == 0) ? w0 : (blockIdx.z == 1) ? w1
                   : (blockIdx.z == 2) ? w2 : (blockIdx.z == 3) ? w3 : w4;
  u16* out = dst + (size_t)blockIdx.z * HIDDEN * HIDDEN;
  __shared__ float tile[64 * 65];
  int k0 = blockIdx.y * 64, c0 = blockIdx.x * 64;
  int tid = threadIdx.x;
#pragma unroll
  for (int j = 0; j < 16; ++j) {
    int f = j * 256 + tid;
    int r = f >> 6, c = f & 63;
    tile[r * 65 + c] = src[(size_t)(k0 + r) * HIDDEN + c0 + c];
  }
  __syncthreads();
#pragma unroll
  for (int j = 0; j < 16; ++j) {
    int f = j * 256 + tid;
    int cc = f >> 6, kk = f & 63;
    out[(size_t)(c0 + cc) * HIDDEN + k0 + kk] = f2bf(tile[kk * 65 + cc]);
  }
}

// ---------------- 256x256 GEMM body, BK=32, 8 waves (2Mx4N) -----------------
// LDS tile [256 r][4 chunks of 8 u16]; chunk' = chunk ^ ((r>>1)&3)  (verified
// round-4 algebra; cs8 identical since m*8 == 0 mod 4).
// MODE 0: rope epilogue -> bf16 [bh][n][d]   (q, k)
// MODE 1: bf16 transposed [bh][d][n]         (v)  — ushort4 stores
// MODE 2: bf16 [t][c]                        (g)
// MODE 3: fp32 [t][c]                        (final out)
// c0r: column base within the 2048-wide weight (for epilogue d/h split).
template <int MODE>
__device__ __forceinline__ void gemm_body(const u16* __restrict__ A,
                                          const u16* __restrict__ Bt,
                                          const float* __restrict__ bias,
                                          void* __restrict__ out,
                                          int by, int c0r, u16* Ab, u16* Bb) {
  const int tid = threadIdx.x;
  const int l = tid & 63, w = tid >> 6;
  const int wm = w >> 2, wn = w & 3;
  const int t0 = by * 256;
  const int lr = l & 15;
  const int cs8 = (((l >> 4) ^ ((lr >> 1) & 3)) * 8);  // swizzled k-chunk
  const int ci0 = tid, ci1 = tid + 512;
  const size_t aoff0 = (size_t)(t0 + (ci0 >> 2)) * HIDDEN + (((ci0 & 3) ^ ((ci0 >> 3) & 3)) * 8);
  const size_t aoff1 = (size_t)(t0 + (ci1 >> 2)) * HIDDEN + (((ci1 & 3) ^ ((ci1 >> 3) & 3)) * 8);
  const size_t boff0 = (size_t)(c0r + (ci0 >> 2)) * HIDDEN + (((ci0 & 3) ^ ((ci0 >> 3) & 3)) * 8);
  const size_t boff1 = (size_t)(c0r + (ci1 >> 2)) * HIDDEN + (((ci1 & 3) ^ ((ci1 >> 3) & 3)) * 8);
  const int ldsb = w * 1024;  // wave-uniform LDS byte base

  f32x4 acc[8][4] = {};
#define GSTAGE(buf, kk)                                                   \
  do {                                                                    \
    async16((char*)Ab + (buf)*16384 + ldsb, A + aoff0 + (kk));            \
    async16((char*)Ab + (buf)*16384 + ldsb + 8192, A + aoff1 + (kk));     \
    async16((char*)Bb + (buf)*16384 + ldsb, Bt + boff0 + (kk));           \
    async16((char*)Bb + (buf)*16384 + ldsb + 8192, Bt + boff1 + (kk));    \
  } while (0)

  GSTAGE(0, 0);
  asm volatile("s_waitcnt vmcnt(0)" ::: "memory");
  __syncthreads();
  int cur = 0;
  for (int kk = 0; kk < HIDDEN; kk += 32) {
    if (kk + 32 < HIDDEN) GSTAGE(cur ^ 1, kk + 32);
    bf16x8 af[8], bfr[4];
#pragma unroll
    for (int m = 0; m < 8; ++m)
      af[m] = *(const bf16x8*)&Ab[cur * 8192 + (wm * 128 + m * 16 + lr) * 32 + cs8];
#pragma unroll
    for (int n = 0; n < 4; ++n)
      bfr[n] = *(const bf16x8*)&Bb[cur * 8192 + (wn * 64 + n * 16 + lr) * 32 + cs8];
#pragma unroll
    for (int m = 0; m < 8; ++m)
#pragma unroll
      for (int n = 0; n < 4; ++n)
        acc[m][n] = __builtin_amdgcn_mfma_f32_16x16x32_bf16(af[m], bfr[n],
                                                            acc[m][n], 0, 0, 0);
    asm volatile("s_waitcnt vmcnt(0)" ::: "memory");
    __syncthreads();
    cur ^= 1;
  }
#undef GSTAGE

#pragma unroll
  for (int m = 0; m < 8; ++m) {
#pragma unroll
    for (int n = 0; n < 4; ++n) {
      int cl = c0r + wn * 64 + n * 16 + lr;
      int tlb = t0 + wm * 128 + m * 16 + (l >> 4) * 4;
      if constexpr (MODE == 1) {
        int d = cl & 255, hh = cl >> 8;
        int nb = tlb & (SEQ - 1), bb = tlb >> 12;
        float bi = bias[cl];
        ushort4 ov;
        ov.x = f2bf(acc[m][n][0] + bi);
        ov.y = f2bf(acc[m][n][1] + bi);
        ov.z = f2bf(acc[m][n][2] + bi);
        ov.w = f2bf(acc[m][n][3] + bi);
        *(ushort4*)&((u16*)out)[((size_t)(bb * HEADS + hh) * HD + d) * SEQ + nb] = ov;
      } else {
#pragma unroll
        for (int r = 0; r < 4; ++r) {
          int tl = tlb + r;
          float val = acc[m][n][r] + bias[cl];
          if constexpr (MODE == 0) {
            float pv = __shfl_xor(val, 1);
            float mi = (cl & 1) ? pv : -pv;  // even: -x_odd, odd: x_even
            int d = cl & 255, hh = cl >> 8;
            int ntok = tl & (SEQ - 1), bb = tl >> 12;
            float theta = exp2f(-(float)(d >> 1) * 0.1046276623f);
            float sv, cv;
            sincosf((float)ntok * theta, &sv, &cv);
            float ov = val * cv + mi * sv;
            ((u16*)out)[((size_t)(bb * HEADS + hh) * SEQ + ntok) * HD + d] = f2bf(ov);
          } else if constexpr (MODE == 2) {
            ((u16*)out)[(size_t)tl * HIDDEN + cl] = f2bf(val);
          } else {
            ((float*)out)[(size_t)tl * HIDDEN + cl] = val;
          }
        }
      }
    }
  }
}

// Fused Q/K/V/G projection: M=8192, N=8192 as 32x32 tiles of 256.
// Remap (bijective, 1024 = 8 XCD x 128): each XCD owns 4 contiguous A-strips,
// sweeps bx inner -> same-bx blocks share B-panel in L2; B L3-hot across XCDs.
__global__ __launch_bounds__(512, 2) void k_gemm_qkvg(
    const u16* __restrict__ A, const u16* __restrict__ wT,
    const float* __restrict__ b_q, const float* __restrict__ b_k,
    const float* __restrict__ b_v, const float* __restrict__ b_g,
    u16* __restrict__ qw, u16* __restrict__ kw, u16* __restrict__ vTw,
    u16* __restrict__ gw) {
  __shared__ __align__(16) u16 Ab[2 * 8192];
  __shared__ __align__(16) u16 Bb[2 * 8192];
  const int id = blockIdx.x;
  const int by = (id & 7) * 4 + ((id >> 3) & 3);  // 0..31
  const int bx = id >> 5;                         // 0..31
  const int wsel = bx >> 3;
  const int c0r = (bx & 7) * 256;
  const size_t WSZ = 4194304;
  switch (wsel) {
    case 0: gemm_body<0>(A, wT,           b_q, (void*)qw,  by, c0r, Ab, Bb); break;
    case 1: gemm_body<0>(A, wT + WSZ,     b_k, (void*)kw,  by, c0r, Ab, Bb); break;
    case 2: gemm_body<1>(A, wT + 2 * WSZ, b_v, (void*)vTw, by, c0r, Ab, Bb); break;
    default: gemm_body<2>(A, wT + 3 * WSZ, b_g, (void*)gw, by, c0r, Ab, Bb); break;
  }
}

// Output projection: M=8192, N=2048 as 32x8 tiles of 256; same remap (256 blk).
__global__ __launch_bounds__(512, 2) void k_gemm_o(const u16* __restrict__ A,
                                                   const u16* __restrict__ Bt,
                                                   const float* __restrict__ bias,
                                                   float* __restrict__ out) {
  __shared__ __align__(16) u16 Ab[2 * 8192];
  __shared__ __align__(16) u16 Bb[2 * 8192];
  const int id = blockIdx.x;
  const int by = (id & 7) * 4 + ((id >> 3) & 3);  // 0..31
  const int bx = id >> 5;                         // 0..7
  gemm_body<3>(A, Bt, bias, (void*)out, by, bx * 256, Ab, Bb);
}

// ---------------- retention attention ----------------
// Tq=128 (8 waves, 512 thr), Tk=32 double-buffered; bh pinned 2-per-XCD.
// (verified round-5 code, unchanged)
__global__ __launch_bounds__(512) void k_attn(const u16* __restrict__ qw,
                                              const u16* __restrict__ kw,
                                              const u16* __restrict__ vTw,
                                              u16* __restrict__ rtb) {
  __shared__ __align__(16) u16 k_lds[2][32 * 256];
  __shared__ __align__(16) u16 vT_lds[2][256 * 32];
  __shared__ __align__(16) u16 P_lds[128 * 32];
  const int id = blockIdx.x;
  const int bh = ((id & 7) << 1) | ((id >> 3) & 1);  // 2 heads per XCD
  const int qx = id >> 4;                            // 0..31
  const int b = bh >> 3, h = bh & 7;
  const int tid = threadIdx.x, l = tid & 63, w = tid >> 6;
  const int lr = l & 15, lk8 = (l >> 4) * 8;
  const int q0 = qx * 128;
  const float log2g = log2f(1.0f - exp2f(-5.0f - 4.0f * (float)h / 7.0f));
  const int cs_v8 = (((l >> 4) ^ ((lr >> 1) & 3)) * 8);
  const int lr7 = lr & 7;

  bf16x8 qf[8];
  {
    const u16* qbase = qw + ((size_t)bh * SEQ + q0 + w * 16 + lr) * HD + lk8;
#pragma unroll
    for (int kd = 0; kd < 8; ++kd) qf[kd] = *(const bf16x8*)(qbase + kd * 32);
  }
  size_t koff[2], voff[2];
#pragma unroll
  for (int j = 0; j < 2; ++j) {
    int ci = tid + 512 * j;  // 0..1023
    koff[j] = ((size_t)bh * SEQ + (ci >> 5)) * HD + (((ci & 31) ^ ((ci >> 5) & 7)) * 8);
    voff[j] = ((size_t)bh * HD + (ci >> 2)) * SEQ + (((ci & 3) ^ ((ci >> 3) & 3)) * 8);
  }
  const int ldsb = w * 1024;

#define ASTAGE(buf, s0)                                                        \
  do {                                                                         \
    _Pragma("unroll") for (int j = 0; j < 2; ++j) {                            \
      async16((char*)&k_lds[buf][0] + ldsb + j * 8192,                         \
              kw + koff[j] + (size_t)(s0)*HD);                                 \
      async16((char*)&vT_lds[buf][0] + ldsb + j * 8192,                        \
              vTw + voff[j] + (size_t)(s0));                                   \
    }                                                                          \
  } while (0)

  f32x4 o[16] = {};
  const int nt = qx * 4 + 4;
  ASTAGE(0, 0);
  asm volatile("s_waitcnt vmcnt(0)" ::: "memory");
  __syncthreads();
  int cur = 0;
  for (int t = 0; t < nt; ++t) {
    const int s0 = t * 32;
    if (t + 1 < nt) ASTAGE(cur ^ 1, s0 + 32);
    f32x4 sf[2] = {};
#pragma unroll
    for (int fc = 0; fc < 2; ++fc) {
      const int R = fc * 16 + lr;
#pragma unroll
      for (int kd = 0; kd < 8; ++kd) {
        bf16x8 kb = *(const bf16x8*)&k_lds[cur][R * 256 + (((kd * 4 + (l >> 4)) ^ lr7) * 8)];
        sf[fc] = __builtin_amdgcn_mfma_f32_16x16x32_bf16(qf[kd], kb, sf[fc], 0, 0, 0);
      }
    }
#pragma unroll
    for (int fc = 0; fc < 2; ++fc) {
      int s_l = fc * 16 + lr;
      int chunk = s_l >> 3;
#pragma unroll
      for (int r = 0; r < 4; ++r) {
        int n_l = w * 16 + (l >> 4) * 4 + r;
        int dist = (q0 + n_l) - (s0 + s_l);
        float p = 0.0f;
        if (dist >= 0) p = sf[fc][r] * 0.0625f * exp2f((float)dist * log2g);
        P_lds[n_l * 32 + ((chunk ^ ((n_l >> 1) & 3)) * 8) + (s_l & 7)] = f2bf(p);
      }
    }
    bf16x8 pa = *(const bf16x8*)&P_lds[(w * 16 + lr) * 32 + cs_v8];
#pragma unroll
    for (int fd = 0; fd < 16; ++fd) {
      bf16x8 vb = *(const bf16x8*)&vT_lds[cur][(fd * 16 + lr) * 32 + cs_v8];
      o[fd] = __builtin_amdgcn_mfma_f32_16x16x32_bf16(pa, vb, o[fd], 0, 0, 0);
    }
    asm volatile("s_waitcnt vmcnt(0)" ::: "memory");
    __syncthreads();
    cur ^= 1;
  }
#undef ASTAGE
  size_t trow = (size_t)b * SEQ + q0 + w * 16 + (l >> 4) * 4;
#pragma unroll
  for (int fd = 0; fd < 16; ++fd) {
    int c = h * HD + fd * 16 + lr;
#pragma unroll
    for (int r = 0; r < 4; ++r)
      rtb[(trow + r) * HIDDEN + c] = f2bf(o[fd][r]);
  }
}

// ---------------- groupnorm + silu gate (in-place on bf16 ret) ----------------
__global__ __launch_bounds__(256) void k_gate(u16* __restrict__ rg,
                                              const u16* __restrict__ gw,
                                              const float* __restrict__ gnw,
                                              const float* __restrict__ gnb) {
  int g = blockIdx.x * 4 + (threadIdx.x >> 6);
  int l = threadIdx.x & 63;
  int t = g >> 3, h = g & 7;
  size_t base = (size_t)t * HIDDEN + h * HD + l * 4;
  ushort4 r4 = *(const ushort4*)(rg + base);
  float rv[4] = {bf2f(r4.x), bf2f(r4.y), bf2f(r4.z), bf2f(r4.w)};
  float s = rv[0] + rv[1] + rv[2] + rv[3];
  float sq = rv[0] * rv[0] + rv[1] * rv[1] + rv[2] * rv[2] + rv[3] * rv[3];
#pragma unroll
  for (int off = 32; off > 0; off >>= 1) {
    s += __shfl_xor(s, off);
    sq += __shfl_xor(sq, off);
  }
  float mean = s * (1.0f / 256.0f);
  float var = sq * (1.0f / 256.0f) - mean * mean;
  float rstd = rsqrtf(var + 1e-5f);
  int cb = h * HD + l * 4;
  float4 wv = *(const float4*)(gnw + cb);
  float4 bv = *(const float4*)(gnb + cb);
  ushort4 gg = *(const ushort4*)(gw + base);
  float gf[4] = {bf2f(gg.x), bf2f(gg.y), bf2f(gg.z), bf2f(gg.w)};
  float wa[4] = {wv.x, wv.y, wv.z, wv.w};
  float ba[4] = {bv.x, bv.y, bv.z, bv.w};
  ushort4 ov;
  u16* po = (u16*)&ov;
#pragma unroll
  for (int e = 0; e < 4; ++e) {
    float nrm = (rv[e] - mean) * rstd * wa[e] + ba[e];
    float gv = gf[e];
    float si = gv / (1.0f + expf(-gv));
    po[e] = f2bf(si * nrm);
  }
  *(ushort4*)(rg + base) = ov;
}

extern "C" void kernel_launch(void* const* d_in, const int* in_sizes, int n_in,
                              void* d_out, int out_size, void* d_ws, size_t ws_size,
                              hipStream_t stream) {
  (void)in_sizes; (void)n_in; (void)out_size; (void)ws_size;
  const float* x   = (const float*)d_in[0];
  const float* w_q = (const float*)d_in[1];
  const float* b_q = (const float*)d_in[2];
  const float* w_k = (const float*)d_in[3];
  const float* b_k = (const float*)d_in[4];
  const float* w_v = (const float*)d_in[5];
  const float* b_v = (const float*)d_in[6];
  const float* w_g = (const float*)d_in[7];
  const float* b_g = (const float*)d_in[8];
  const float* w_o = (const float*)d_in[9];
  const float* b_o = (const float*)d_in[10];
  const float* gnw = (const float*)d_in[11];
  const float* gnb = (const float*)d_in[12];

  // workspace layout — peak 200 MiB
  char* ws = (char*)d_ws;
  u16* xb   = (u16*)(ws);
  u16* wT   = (u16*)(ws + 33554432ULL);
  u16* qw   = (u16*)(ws + 75497472ULL);
  u16* kw   = (u16*)(ws + 109051904ULL);
  u16* vTw  = (u16*)(ws + 142606336ULL);
  u16* gw   = (u16*)(ws + 176160768ULL);
  u16* rtg  = xb;  // ret/gate reuse slot0 (xb dead after qkvg GEMM)

  const size_t WSZ = 4194304;  // elements per transposed weight matrix

  k_cvt_x<<<16384, 256, 0, stream>>>(x, xb);
  k_transpose<<<dim3(32, 32, 5), 256, 0, stream>>>(w_q, w_k, w_v, w_g, w_o, wT);
  k_gemm_qkvg<<<1024, 512, 0, stream>>>(xb, wT, b_q, b_k, b_v, b_g, qw, kw, vTw, gw);
  k_attn<<<512, 512, 0, stream>>>(qw, kw, vTw, rtg);
  k_gate<<<16384, 256, 0, stream>>>(rtg, gw, gnw, gnb);
  k_gemm_o<<<256, 512, 0, stream>>>(rtg, wT + 4 * WSZ, b_o, (float*)d_out);
}

// Round 7
// 913.800 us; speedup vs baseline: 4.0369x; 4.0369x over previous
//
#include <hip/hip_runtime.h>

typedef unsigned short u16;
typedef unsigned int u32;
typedef __bf16 bf16x8 __attribute__((ext_vector_type(8)));
typedef unsigned short u16x8 __attribute__((ext_vector_type(8)));
typedef float f32x4 __attribute__((ext_vector_type(4)));

#define HIDDEN 2048
#define SEQ 4096
#define HEADS 8
#define HD 256

__device__ __forceinline__ u16 f2bf(float f) {
  u32 u = __float_as_uint(f);
  u32 r = (u + 0x7fffu + ((u >> 16) & 1u)) >> 16;
  return (u16)r;
}
__device__ __forceinline__ float bf2f(u16 h) {
  return __uint_as_float(((u32)h) << 16);
}
__device__ __forceinline__ void async16(void* lds, const void* g) {
  __builtin_amdgcn_global_load_lds(
      (__attribute__((address_space(1))) void*)g,
      (__attribute__((address_space(3))) void*)lds, 16, 0, 0);
}

// ---------------- convert x to bf16 ----------------
__global__ __launch_bounds__(256) void k_cvt_x(const float* __restrict__ x,
                                               u16* __restrict__ xb) {
  int i = blockIdx.x * 256 + threadIdx.x;
  float4 v = ((const float4*)x)[i];
  ushort4 o;
  o.x = f2bf(v.x); o.y = f2bf(v.y); o.z = f2bf(v.z); o.w = f2bf(v.w);
  ((ushort4*)xb)[i] = o;
}

// ---------------- transpose weights to bf16 W^T[c][k] ----------------
__global__ __launch_bounds__(256) void k_transpose(
    const float* __restrict__ w0, const float* __restrict__ w1,
    const float* __restrict__ w2, const float* __restrict__ w3,
    const float* __restrict__ w4, u16* __restrict__ dst) {
  const float* src = (blockIdx.z == 0) ? w0 : (blockIdx.z == 1) ? w1
                   : (blockIdx.z == 2) ? w2 : (blockIdx.z == 3) ? w3 : w4;
  u16* out = dst + (size_t)blockIdx.z * HIDDEN * HIDDEN;
  __shared__ float tile[64 * 65];
  int k0 = blockIdx.y * 64, c0 = blockIdx.x * 64;
  int tid = threadIdx.x;
#pragma unroll
  for (int j = 0; j < 16; ++j) {
    int f = j * 256 + tid;
    int r = f >> 6, c = f & 63;
    tile[r * 65 + c] = src[(size_t)(k0 + r) * HIDDEN + c0 + c];
  }
  __syncthreads();
#pragma unroll
  for (int j = 0; j < 16; ++j) {
    int f = j * 256 + tid;
    int cc = f >> 6, kk = f & 63;
    out[(size_t)(c0 + cc) * HIDDEN + k0 + kk] = f2bf(tile[kk * 65 + cc]);
  }
}

// ---------------- 128x128 GEMM body, BK=32, 4 waves (round-4 verified core) --
// New epilogue: per-wave LDS C-tile stage -> full-cacheline stores.
// MODE 0: rope -> bf16 [bh][n][d]   (q, k)   16B/lane, 128B/8-lane line
// MODE 1: bf16 transposed [bh][d][n] (v)     line = 64 ntok at fixed d
// MODE 2: bf16 [t][c]                (g)
// MODE 3: fp32 [t][c]                (final out), per-m f32 stage
template <int MODE>
__device__ __forceinline__ void gemm_body(const u16* __restrict__ A,
                                          const u16* __restrict__ Bt,
                                          const float* __restrict__ bias,
                                          void* __restrict__ out,
                                          int bx, int by, u16* Ab, u16* Bb) {
  const int tid = threadIdx.x;
  const int l = tid & 63, w = tid >> 6;
  const int wr = w >> 1, wc = w & 1;
  const int t0 = by * 128, c0 = bx * 128;
  const int lr = l & 15;
  const int cs8 = (((l >> 4) ^ ((lr >> 1) & 3)) * 8);  // swizzled k-chunk
  const int ci0 = tid, ci1 = tid + 256;
  const size_t aoff0 = (size_t)(t0 + (ci0 >> 2)) * HIDDEN + (((ci0 & 3) ^ ((ci0 >> 3) & 3)) * 8);
  const size_t aoff1 = (size_t)(t0 + (ci1 >> 2)) * HIDDEN + (((ci1 & 3) ^ ((ci1 >> 3) & 3)) * 8);
  const size_t boff0 = (size_t)(c0 + (ci0 >> 2)) * HIDDEN + (((ci0 & 3) ^ ((ci0 >> 3) & 3)) * 8);
  const size_t boff1 = (size_t)(c0 + (ci1 >> 2)) * HIDDEN + (((ci1 & 3) ^ ((ci1 >> 3) & 3)) * 8);
  const int ldsb = w * 1024;  // wave-uniform LDS byte base

  f32x4 acc[4][4] = {};
#define GSTAGE(buf, kk)                                                  \
  do {                                                                   \
    async16((char*)Ab + (buf)*8192 + ldsb, A + aoff0 + (kk));            \
    async16((char*)Ab + (buf)*8192 + ldsb + 4096, A + aoff1 + (kk));     \
    async16((char*)Bb + (buf)*8192 + ldsb, Bt + boff0 + (kk));           \
    async16((char*)Bb + (buf)*8192 + ldsb + 4096, Bt + boff1 + (kk));    \
  } while (0)

  GSTAGE(0, 0);
  asm volatile("s_waitcnt vmcnt(0)" ::: "memory");
  __syncthreads();
  int cur = 0;
  for (int kk = 0; kk < HIDDEN; kk += 32) {
    if (kk + 32 < HIDDEN) GSTAGE(cur ^ 1, kk + 32);
    bf16x8 af[4], bfr[4];
#pragma unroll
    for (int m = 0; m < 4; ++m)
      af[m] = *(const bf16x8*)&Ab[cur * 4096 + (wr * 64 + m * 16 + lr) * 32 + cs8];
#pragma unroll
    for (int n = 0; n < 4; ++n)
      bfr[n] = *(const bf16x8*)&Bb[cur * 4096 + (wc * 64 + n * 16 + lr) * 32 + cs8];
#pragma unroll
    for (int m = 0; m < 4; ++m)
#pragma unroll
      for (int n = 0; n < 4; ++n)
        acc[m][n] = __builtin_amdgcn_mfma_f32_16x16x32_bf16(af[m], bfr[n],
                                                            acc[m][n], 0, 0, 0);
    asm volatile("s_waitcnt vmcnt(0)" ::: "memory");
    __syncthreads();
    cur ^= 1;
  }
#undef GSTAGE
  // ---- epilogue: after this barrier staging LDS is dead; per-wave scratch,
  // no cross-wave sharing, so wave-local lgkmcnt ordering suffices below.
  if constexpr (MODE == 3) {
    float* scf = (float*)Ab + w * 1024;  // 16x64 f32 per wave, unit-XOR swizzle
    for (int m = 0; m < 4; ++m) {
#pragma unroll
      for (int n = 0; n < 4; ++n) {
        int cl = c0 + wc * 64 + n * 16 + lr;
        float bi = bias[cl];
        int unit = n * 4 + (lr >> 2);
#pragma unroll
        for (int r = 0; r < 4; ++r) {
          int row = (l >> 4) * 4 + r;
          scf[row * 64 + ((unit ^ row) & 15) * 4 + (lr & 3)] = acc[m][n][r] + bi;
        }
      }
#pragma unroll
      for (int p = 0; p < 4; ++p) {
        int row = (l >> 4) + p * 4;
        int unit = l & 15;
        f32x4 v4 = *(f32x4*)&scf[row * 64 + ((unit ^ row) & 15) * 4];
        int tl = t0 + wr * 64 + m * 16 + row;
        *(f32x4*)&((float*)out)[(size_t)tl * HIDDEN + c0 + wc * 64 + unit * 4] = v4;
      }
    }
  } else {
    u16* scr = (w < 2) ? (Ab + w * 4096) : (Bb + (w - 2) * 4096);  // 64x64 u16
#pragma unroll
    for (int m = 0; m < 4; ++m)
#pragma unroll
      for (int n = 0; n < 4; ++n) {
        int cl = c0 + wc * 64 + n * 16 + lr;
        float bi = bias[cl];
#pragma unroll
        for (int r = 0; r < 4; ++r) {
          int trow = m * 16 + (l >> 4) * 4 + r;  // local ntok
          int tcol = n * 16 + lr;                // local c
          int row = (MODE == 1) ? tcol : trow;
          int col = (MODE == 1) ? trow : tcol;
          scr[row * 64 + (((col >> 3) ^ (row & 7)) * 8) + (col & 7)] =
              f2bf(acc[m][n][r] + bi);
        }
      }
#pragma unroll
    for (int p = 0; p < 8; ++p) {
      int row = (l >> 3) + p * 8;
      int ch = (l & 7) ^ (row & 7);
      bf16x8 v = *(bf16x8*)&scr[row * 64 + ch * 8];
      int colb = (l & 7) * 8;
      if constexpr (MODE == 0) {
        int tl = t0 + wr * 64 + row;
        int cb = c0 + wc * 64 + colb;
        int d = cb & 255, hh = cb >> 8;
        int ntok = tl & (SEQ - 1), bb = tl >> 12;
        u16x8 ov;
#pragma unroll
        for (int jp = 0; jp < 4; ++jp) {
          float theta = exp2f(-(float)((d >> 1) + jp) * 0.1046276623f);
          float sv, cv;
          sincosf((float)ntok * theta, &sv, &cv);
          float e = (float)v[2 * jp], o = (float)v[2 * jp + 1];
          ov[2 * jp] = f2bf(e * cv - o * sv);
          ov[2 * jp + 1] = f2bf(o * cv + e * sv);
        }
        *(u16x8*)&((u16*)out)[((size_t)(bb * HEADS + hh) * SEQ + ntok) * HD + d] = ov;
      } else if constexpr (MODE == 1) {
        int dfull = c0 + wc * 64 + row;  // row = local d
        int d = dfull & 255, hh = dfull >> 8;
        int ntg = t0 + wr * 64 + colb;  // colb = local ntok base
        int nb = ntg & (SEQ - 1), bb = ntg >> 12;
        *(u16x8*)&((u16*)out)[((size_t)(bb * HEADS + hh) * HD + d) * SEQ + nb] =
            *(u16x8*)&v;
      } else {
        int tl = t0 + wr * 64 + row;
        *(u16x8*)&((u16*)out)[(size_t)tl * HIDDEN + c0 + wc * 64 + colb] =
            *(u16x8*)&v;
      }
    }
  }
}

#define GEMM_KERNEL(NAME, MODE, OUTT)                                         \
  __global__ __launch_bounds__(256) void NAME(                                \
      const u16* __restrict__ A, const u16* __restrict__ Bt,                  \
      const float* __restrict__ bias, OUTT* __restrict__ out) {               \
    __shared__ __align__(16) u16 Ab[8192];                                    \
    __shared__ __align__(16) u16 Bb[8192];                                    \
    gemm_body<MODE>(A, Bt, bias, (void*)out, blockIdx.x, blockIdx.y, Ab, Bb); \
  }

GEMM_KERNEL(k_gemm_q, 0, u16)
GEMM_KERNEL(k_gemm_k, 0, u16)
GEMM_KERNEL(k_gemm_v, 1, u16)
GEMM_KERNEL(k_gemm_g, 2, u16)
GEMM_KERNEL(k_gemm_o, 3, float)

// ---------------- retention attention ----------------
// Tq=128 (8 waves, 512 thr), Tk=32 double-buffered; bh pinned 2-per-XCD.
// (verified round-5/6 code, unchanged)
__global__ __launch_bounds__(512) void k_attn(const u16* __restrict__ qw,
                                              const u16* __restrict__ kw,
                                              const u16* __restrict__ vTw,
                                              u16* __restrict__ rtb) {
  __shared__ __align__(16) u16 k_lds[2][32 * 256];
  __shared__ __align__(16) u16 vT_lds[2][256 * 32];
  __shared__ __align__(16) u16 P_lds[128 * 32];
  const int id = blockIdx.x;
  const int bh = ((id & 7) << 1) | ((id >> 3) & 1);  // 2 heads per XCD
  const int qx = id >> 4;                            // 0..31
  const int b = bh >> 3, h = bh & 7;
  const int tid = threadIdx.x, l = tid & 63, w = tid >> 6;
  const int lr = l & 15, lk8 = (l >> 4) * 8;
  const int q0 = qx * 128;
  const float log2g = log2f(1.0f - exp2f(-5.0f - 4.0f * (float)h / 7.0f));
  const int cs_v8 = (((l >> 4) ^ ((lr >> 1) & 3)) * 8);
  const int lr7 = lr & 7;

  bf16x8 qf[8];
  {
    const u16* qbase = qw + ((size_t)bh * SEQ + q0 + w * 16 + lr) * HD + lk8;
#pragma unroll
    for (int kd = 0; kd < 8; ++kd) qf[kd] = *(const bf16x8*)(qbase + kd * 32);
  }
  size_t koff[2], voff[2];
#pragma unroll
  for (int j = 0; j < 2; ++j) {
    int ci = tid + 512 * j;  // 0..1023
    koff[j] = ((size_t)bh * SEQ + (ci >> 5)) * HD + (((ci & 31) ^ ((ci >> 5) & 7)) * 8);
    voff[j] = ((size_t)bh * HD + (ci >> 2)) * SEQ + (((ci & 3) ^ ((ci >> 3) & 3)) * 8);
  }
  const int ldsb = w * 1024;

#define ASTAGE(buf, s0)                                                        \
  do {                                                                         \
    _Pragma("unroll") for (int j = 0; j < 2; ++j) {                            \
      async16((char*)&k_lds[buf][0] + ldsb + j * 8192,                         \
              kw + koff[j] + (size_t)(s0)*HD);                                 \
      async16((char*)&vT_lds[buf][0] + ldsb + j * 8192,                        \
              vTw + voff[j] + (size_t)(s0));                                   \
    }                                                                          \
  } while (0)

  f32x4 o[16] = {};
  const int nt = qx * 4 + 4;
  ASTAGE(0, 0);
  asm volatile("s_waitcnt vmcnt(0)" ::: "memory");
  __syncthreads();
  int cur = 0;
  for (int t = 0; t < nt; ++t) {
    const int s0 = t * 32;
    if (t + 1 < nt) ASTAGE(cur ^ 1, s0 + 32);
    f32x4 sf[2] = {};
#pragma unroll
    for (int fc = 0; fc < 2; ++fc) {
      const int R = fc * 16 + lr;
#pragma unroll
      for (int kd = 0; kd < 8; ++kd) {
        bf16x8 kb = *(const bf16x8*)&k_lds[cur][R * 256 + (((kd * 4 + (l >> 4)) ^ lr7) * 8)];
        sf[fc] = __builtin_amdgcn_mfma_f32_16x16x32_bf16(qf[kd], kb, sf[fc], 0, 0, 0);
      }
    }
#pragma unroll
    for (int fc = 0; fc < 2; ++fc) {
      int s_l = fc * 16 + lr;
      int chunk = s_l >> 3;
#pragma unroll
      for (int r = 0; r < 4; ++r) {
        int n_l = w * 16 + (l >> 4) * 4 + r;
        int dist = (q0 + n_l) - (s0 + s_l);
        float p = 0.0f;
        if (dist >= 0) p = sf[fc][r] * 0.0625f * exp2f((float)dist * log2g);
        P_lds[n_l * 32 + ((chunk ^ ((n_l >> 1) & 3)) * 8) + (s_l & 7)] = f2bf(p);
      }
    }
    bf16x8 pa = *(const bf16x8*)&P_lds[(w * 16 + lr) * 32 + cs_v8];
#pragma unroll
    for (int fd = 0; fd < 16; ++fd) {
      bf16x8 vb = *(const bf16x8*)&vT_lds[cur][(fd * 16 + lr) * 32 + cs_v8];
      o[fd] = __builtin_amdgcn_mfma_f32_16x16x32_bf16(pa, vb, o[fd], 0, 0, 0);
    }
    asm volatile("s_waitcnt vmcnt(0)" ::: "memory");
    __syncthreads();
    cur ^= 1;
  }
#undef ASTAGE
  size_t trow = (size_t)b * SEQ + q0 + w * 16 + (l >> 4) * 4;
#pragma unroll
  for (int fd = 0; fd < 16; ++fd) {
    int c = h * HD + fd * 16 + lr;
#pragma unroll
    for (int r = 0; r < 4; ++r)
      rtb[(trow + r) * HIDDEN + c] = f2bf(o[fd][r]);
  }
}

// ---------------- groupnorm + silu gate (in-place on bf16 ret) ----------------
__global__ __launch_bounds__(256) void k_gate(u16* __restrict__ rg,
                                              const u16* __restrict__ gw,
                                              const float* __restrict__ gnw,
                                              const float* __restrict__ gnb) {
  int g = blockIdx.x * 4 + (threadIdx.x >> 6);
  int l = threadIdx.x & 63;
  int t = g >> 3, h = g & 7;
  size_t base = (size_t)t * HIDDEN + h * HD + l * 4;
  ushort4 r4 = *(const ushort4*)(rg + base);
  float rv[4] = {bf2f(r4.x), bf2f(r4.y), bf2f(r4.z), bf2f(r4.w)};
  float s = rv[0] + rv[1] + rv[2] + rv[3];
  float sq = rv[0] * rv[0] + rv[1] * rv[1] + rv[2] * rv[2] + rv[3] * rv[3];
#pragma unroll
  for (int off = 32; off > 0; off >>= 1) {
    s += __shfl_xor(s, off);
    sq += __shfl_xor(sq, off);
  }
  float mean = s * (1.0f / 256.0f);
  float var = sq * (1.0f / 256.0f) - mean * mean;
  float rstd = rsqrtf(var + 1e-5f);
  int cb = h * HD + l * 4;
  float4 wv = *(const float4*)(gnw + cb);
  float4 bv = *(const float4*)(gnb + cb);
  ushort4 gg = *(const ushort4*)(gw + base);
  float gf[4] = {bf2f(gg.x), bf2f(gg.y), bf2f(gg.z), bf2f(gg.w)};
  float wa[4] = {wv.x, wv.y, wv.z, wv.w};
  float ba[4] = {bv.x, bv.y, bv.z, bv.w};
  ushort4 ov;
  u16* po = (u16*)&ov;
#pragma unroll
  for (int e = 0; e < 4; ++e) {
    float nrm = (rv[e] - mean) * rstd * wa[e] + ba[e];
    float gv = gf[e];
    float si = gv / (1.0f + expf(-gv));
    po[e] = f2bf(si * nrm);
  }
  *(ushort4*)(rg + base) = ov;
}

extern "C" void kernel_launch(void* const* d_in, const int* in_sizes, int n_in,
                              void* d_out, int out_size, void* d_ws, size_t ws_size,
                              hipStream_t stream) {
  (void)in_sizes; (void)n_in; (void)out_size; (void)ws_size;
  const float* x   = (const float*)d_in[0];
  const float* w_q = (const float*)d_in[1];
  const float* b_q = (const float*)d_in[2];
  const float* w_k = (const float*)d_in[3];
  const float* b_k = (const float*)d_in[4];
  const float* w_v = (const float*)d_in[5];
  const float* b_v = (const float*)d_in[6];
  const float* w_g = (const float*)d_in[7];
  const float* b_g = (const float*)d_in[8];
  const float* w_o = (const float*)d_in[9];
  const float* b_o = (const float*)d_in[10];
  const float* gnw = (const float*)d_in[11];
  const float* gnb = (const float*)d_in[12];

  // workspace layout — peak 200 MiB
  char* ws = (char*)d_ws;
  u16* xb   = (u16*)(ws);
  u16* wT   = (u16*)(ws + 33554432ULL);
  u16* qw   = (u16*)(ws + 75497472ULL);
  u16* kw   = (u16*)(ws + 109051904ULL);
  u16* vTw  = (u16*)(ws + 142606336ULL);
  u16* gw   = (u16*)(ws + 176160768ULL);
  u16* rtg  = xb;  // ret/gate reuse slot0 (xb dead after projections)

  const size_t WSZ = 4194304;  // elements per transposed weight matrix

  k_cvt_x<<<16384, 256, 0, stream>>>(x, xb);
  k_transpose<<<dim3(32, 32, 5), 256, 0, stream>>>(w_q, w_k, w_v, w_g, w_o, wT);
  k_gemm_q<<<dim3(16, 64), 256, 0, stream>>>(xb, wT,           b_q, qw);
  k_gemm_k<<<dim3(16, 64), 256, 0, stream>>>(xb, wT + WSZ,     b_k, kw);
  k_gemm_v<<<dim3(16, 64), 256, 0, stream>>>(xb, wT + 2 * WSZ, b_v, vTw);
  k_gemm_g<<<dim3(16, 64), 256, 0, stream>>>(xb, wT + 3 * WSZ, b_g, gw);
  k_attn<<<512, 512, 0, stream>>>(qw, kw, vTw, rtg);
  k_gate<<<16384, 256, 0, stream>>>(rtg, gw, gnw, gnb);
  k_gemm_o<<<dim3(16, 64), 256, 0, stream>>>(rtg, wT + 4 * WSZ, b_o, (float*)d_out);
}

// Round 9
// 746.702 us; speedup vs baseline: 4.9403x; 1.2238x over previous
//
#include <hip/hip_runtime.h>

typedef unsigned short u16;
typedef unsigned int u32;
typedef __bf16 bf16x8 __attribute__((ext_vector_type(8)));
typedef unsigned short u16x8 __attribute__((ext_vector_type(8)));
typedef float f32x4 __attribute__((ext_vector_type(4)));

#define HIDDEN 2048
#define SEQ 4096
#define HEADS 8
#define HD 256

__device__ __forceinline__ u16 f2bf(float f) {
  u32 u = __float_as_uint(f);
  u32 r = (u + 0x7fffu + ((u >> 16) & 1u)) >> 16;
  return (u16)r;
}
__device__ __forceinline__ float bf2f(u16 h) {
  return __uint_as_float(((u32)h) << 16);
}
__device__ __forceinline__ void async16(void* lds, const void* g) {
  __builtin_amdgcn_global_load_lds(
      (__attribute__((address_space(1))) void*)g,
      (__attribute__((address_space(3))) void*)lds, 16, 0, 0);
}

// ---------------- convert x to bf16 ----------------
__global__ __launch_bounds__(256) void k_cvt_x(const float* __restrict__ x,
                                               u16* __restrict__ xb) {
  int i = blockIdx.x * 256 + threadIdx.x;
  float4 v = ((const float4*)x)[i];
  ushort4 o;
  o.x = f2bf(v.x); o.y = f2bf(v.y); o.z = f2bf(v.z); o.w = f2bf(v.w);
  ((ushort4*)xb)[i] = o;
}

// ---------------- transpose weights to bf16 W^T[c][k] ----------------
__global__ __launch_bounds__(256) void k_transpose(
    const float* __restrict__ w0, const float* __restrict__ w1,
    const float* __restrict__ w2, const float* __restrict__ w3,
    const float* __restrict__ w4, u16* __restrict__ dst) {
  const float* src = (blockIdx.z == 0) ? w0 : (blockIdx.z == 1) ? w1
                   : (blockIdx.z == 2) ? w2 : (blockIdx.z == 3) ? w3 : w4;
  u16* out = dst + (size_t)blockIdx.z * HIDDEN * HIDDEN;
  __shared__ float tile[64 * 65];
  int k0 = blockIdx.y * 64, c0 = blockIdx.x * 64;
  int tid = threadIdx.x;
#pragma unroll
  for (int j = 0; j < 16; ++j) {
    int f = j * 256 + tid;
    int r = f >> 6, c = f & 63;
    tile[r * 65 + c] = src[(size_t)(k0 + r) * HIDDEN + c0 + c];
  }
  __syncthreads();
#pragma unroll
  for (int j = 0; j < 16; ++j) {
    int f = j * 256 + tid;
    int cc = f >> 6, kk = f & 63;
    out[(size_t)(c0 + cc) * HIDDEN + k0 + kk] = f2bf(tile[kk * 65 + cc]);
  }
}

// ---------------- bf16 transpose: kw [bh][n][d] -> kTw [bh][d][n] ------------
// 64x64 tile, ushort4 loads/stores: 1024 vec4 ops / 256 threads = 4 iters.
__global__ __launch_bounds__(256) void k_transpose_k(const u16* __restrict__ kw,
                                                     u16* __restrict__ kTw) {
  __shared__ u16 tile[64][65];
  const int d0 = blockIdx.x * 64, n0 = blockIdx.y * 64;
  const int bh = blockIdx.z;
  const u16* src = kw + (size_t)bh * SEQ * HD;
  u16* dst = kTw + (size_t)bh * HD * SEQ;
  const int tid = threadIdx.x;
#pragma unroll
  for (int j = 0; j < 4; ++j) {
    int f = j * 256 + tid;
    int r = f >> 4, c4 = (f & 15) * 4;
    ushort4 v = *(const ushort4*)&src[(size_t)(n0 + r) * HD + d0 + c4];
    tile[r][c4] = v.x; tile[r][c4 + 1] = v.y;
    tile[r][c4 + 2] = v.z; tile[r][c4 + 3] = v.w;
  }
  __syncthreads();
#pragma unroll
  for (int j = 0; j < 4; ++j) {
    int f = j * 256 + tid;
    int dr = f >> 4, n4 = (f & 15) * 4;
    ushort4 o;
    o.x = tile[n4][dr]; o.y = tile[n4 + 1][dr];
    o.z = tile[n4 + 2][dr]; o.w = tile[n4 + 3][dr];
    *(ushort4*)&dst[(size_t)(d0 + dr) * SEQ + n0 + n4] = o;
  }
}

// ---------------- 128x128 GEMM body (round-7 verified, unchanged) -----------
template <int MODE>
__device__ __forceinline__ void gemm_body(const u16* __restrict__ A,
                                          const u16* __restrict__ Bt,
                                          const float* __restrict__ bias,
                                          void* __restrict__ out,
                                          int bx, int by, u16* Ab, u16* Bb) {
  const int tid = threadIdx.x;
  const int l = tid & 63, w = tid >> 6;
  const int wr = w >> 1, wc = w & 1;
  const int t0 = by * 128, c0 = bx * 128;
  const int lr = l & 15;
  const int cs8 = (((l >> 4) ^ ((lr >> 1) & 3)) * 8);
  const int ci0 = tid, ci1 = tid + 256;
  const size_t aoff0 = (size_t)(t0 + (ci0 >> 2)) * HIDDEN + (((ci0 & 3) ^ ((ci0 >> 3) & 3)) * 8);
  const size_t aoff1 = (size_t)(t0 + (ci1 >> 2)) * HIDDEN + (((ci1 & 3) ^ ((ci1 >> 3) & 3)) * 8);
  const size_t boff0 = (size_t)(c0 + (ci0 >> 2)) * HIDDEN + (((ci0 & 3) ^ ((ci0 >> 3) & 3)) * 8);
  const size_t boff1 = (size_t)(c0 + (ci1 >> 2)) * HIDDEN + (((ci1 & 3) ^ ((ci1 >> 3) & 3)) * 8);
  const int ldsb = w * 1024;

  f32x4 acc[4][4] = {};
#define GSTAGE(buf, kk)                                                  \
  do {                                                                   \
    async16((char*)Ab + (buf)*8192 + ldsb, A + aoff0 + (kk));            \
    async16((char*)Ab + (buf)*8192 + ldsb + 4096, A + aoff1 + (kk));     \
    async16((char*)Bb + (buf)*8192 + ldsb, Bt + boff0 + (kk));           \
    async16((char*)Bb + (buf)*8192 + ldsb + 4096, Bt + boff1 + (kk));    \
  } while (0)

  GSTAGE(0, 0);
  asm volatile("s_waitcnt vmcnt(0)" ::: "memory");
  __syncthreads();
  int cur = 0;
  for (int kk = 0; kk < HIDDEN; kk += 32) {
    if (kk + 32 < HIDDEN) GSTAGE(cur ^ 1, kk + 32);
    bf16x8 af[4], bfr[4];
#pragma unroll
    for (int m = 0; m < 4; ++m)
      af[m] = *(const bf16x8*)&Ab[cur * 4096 + (wr * 64 + m * 16 + lr) * 32 + cs8];
#pragma unroll
    for (int n = 0; n < 4; ++n)
      bfr[n] = *(const bf16x8*)&Bb[cur * 4096 + (wc * 64 + n * 16 + lr) * 32 + cs8];
#pragma unroll
    for (int m = 0; m < 4; ++m)
#pragma unroll
      for (int n = 0; n < 4; ++n)
        acc[m][n] = __builtin_amdgcn_mfma_f32_16x16x32_bf16(af[m], bfr[n],
                                                            acc[m][n], 0, 0, 0);
    asm volatile("s_waitcnt vmcnt(0)" ::: "memory");
    __syncthreads();
    cur ^= 1;
  }
#undef GSTAGE
  if constexpr (MODE == 3) {
    float* scf = (float*)Ab + w * 1024;
    for (int m = 0; m < 4; ++m) {
#pragma unroll
      for (int n = 0; n < 4; ++n) {
        int cl = c0 + wc * 64 + n * 16 + lr;
        float bi = bias[cl];
        int unit = n * 4 + (lr >> 2);
#pragma unroll
        for (int r = 0; r < 4; ++r) {
          int row = (l >> 4) * 4 + r;
          scf[row * 64 + ((unit ^ row) & 15) * 4 + (lr & 3)] = acc[m][n][r] + bi;
        }
      }
#pragma unroll
      for (int p = 0; p < 4; ++p) {
        int row = (l >> 4) + p * 4;
        int unit = l & 15;
        f32x4 v4 = *(f32x4*)&scf[row * 64 + ((unit ^ row) & 15) * 4];
        int tl = t0 + wr * 64 + m * 16 + row;
        *(f32x4*)&((float*)out)[(size_t)tl * HIDDEN + c0 + wc * 64 + unit * 4] = v4;
      }
    }
  } else {
    u16* scr = (w < 2) ? (Ab + w * 4096) : (Bb + (w - 2) * 4096);
#pragma unroll
    for (int m = 0; m < 4; ++m)
#pragma unroll
      for (int n = 0; n < 4; ++n) {
        int cl = c0 + wc * 64 + n * 16 + lr;
        float bi = bias[cl];
#pragma unroll
        for (int r = 0; r < 4; ++r) {
          int trow = m * 16 + (l >> 4) * 4 + r;
          int tcol = n * 16 + lr;
          int row = (MODE == 1) ? tcol : trow;
          int col = (MODE == 1) ? trow : tcol;
          scr[row * 64 + (((col >> 3) ^ (row & 7)) * 8) + (col & 7)] =
              f2bf(acc[m][n][r] + bi);
        }
      }
#pragma unroll
    for (int p = 0; p < 8; ++p) {
      int row = (l >> 3) + p * 8;
      int ch = (l & 7) ^ (row & 7);
      bf16x8 v = *(bf16x8*)&scr[row * 64 + ch * 8];
      int colb = (l & 7) * 8;
      if constexpr (MODE == 0) {
        int tl = t0 + wr * 64 + row;
        int cb = c0 + wc * 64 + colb;
        int d = cb & 255, hh = cb >> 8;
        int ntok = tl & (SEQ - 1), bb = tl >> 12;
        u16x8 ov;
#pragma unroll
        for (int jp = 0; jp < 4; ++jp) {
          float theta = exp2f(-(float)((d >> 1) + jp) * 0.1046276623f);
          float sv, cv;
          sincosf((float)ntok * theta, &sv, &cv);
          float e = (float)v[2 * jp], o = (float)v[2 * jp + 1];
          ov[2 * jp] = f2bf(e * cv - o * sv);
          ov[2 * jp + 1] = f2bf(o * cv + e * sv);
        }
        *(u16x8*)&((u16*)out)[((size_t)(bb * HEADS + hh) * SEQ + ntok) * HD + d] = ov;
      } else if constexpr (MODE == 1) {
        int dfull = c0 + wc * 64 + row;
        int d = dfull & 255, hh = dfull >> 8;
        int ntg = t0 + wr * 64 + colb;
        int nb = ntg & (SEQ - 1), bb = ntg >> 12;
        *(u16x8*)&((u16*)out)[((size_t)(bb * HEADS + hh) * HD + d) * SEQ + nb] =
            *(u16x8*)&v;
      } else {
        int tl = t0 + wr * 64 + row;
        *(u16x8*)&((u16*)out)[(size_t)tl * HIDDEN + c0 + wc * 64 + colb] =
            *(u16x8*)&v;
      }
    }
  }
}

#define GEMM_KERNEL(NAME, MODE, OUTT)                                         \
  __global__ __launch_bounds__(256) void NAME(                                \
      const u16* __restrict__ A, const u16* __restrict__ Bt,                  \
      const float* __restrict__ bias, OUTT* __restrict__ out) {               \
    __shared__ __align__(16) u16 Ab[8192];                                    \
    __shared__ __align__(16) u16 Bb[8192];                                    \
    gemm_body<MODE>(A, Bt, bias, (void*)out, blockIdx.x, blockIdx.y, Ab, Bb); \
  }

GEMM_KERNEL(k_gemm_q, 0, u16)
GEMM_KERNEL(k_gemm_k, 0, u16)
GEMM_KERNEL(k_gemm_v, 1, u16)
GEMM_KERNEL(k_gemm_g, 2, u16)
GEMM_KERNEL(k_gemm_o, 3, float)

// ---------------- chunk state build: dS_T[c][bh][d_v][d_k] (C=256) ----------
// dS_T = sum_delta gamma^(255-delta) * v[delta][d_v] * k[delta][d_k]
__global__ __launch_bounds__(256) void k_dstate(const u16* __restrict__ vTw,
                                                const u16* __restrict__ kTw,
                                                u16* __restrict__ dS) {
  __shared__ __align__(16) u16 Ab[2 * 4096];
  __shared__ __align__(16) u16 Bb[2 * 4096];
  const int byv = blockIdx.x >> 1, bxk = blockIdx.x & 1;
  const int c = blockIdx.y, bh = blockIdx.z;
  const int h = bh & 7;
  const float log2g = log2f(1.0f - exp2f(-5.0f - 4.0f * (float)h / 7.0f));
  const int tid = threadIdx.x, l = tid & 63, w = tid >> 6;
  const int wr = w >> 1, wc = w & 1;
  const int lr = l & 15, hi = l >> 4;
  const int cs8 = ((hi ^ ((lr >> 1) & 3)) * 8);
  const int ci0 = tid, ci1 = tid + 256;
  const size_t abase = ((size_t)bh * HD + byv * 128) * SEQ + (size_t)c * 256;
  const size_t bbase = ((size_t)bh * HD + bxk * 128) * SEQ + (size_t)c * 256;
  const size_t aoff0 = abase + (size_t)(ci0 >> 2) * SEQ + (((ci0 & 3) ^ ((ci0 >> 3) & 3)) * 8);
  const size_t aoff1 = abase + (size_t)(ci1 >> 2) * SEQ + (((ci1 & 3) ^ ((ci1 >> 3) & 3)) * 8);
  const size_t boff0 = bbase + (size_t)(ci0 >> 2) * SEQ + (((ci0 & 3) ^ ((ci0 >> 3) & 3)) * 8);
  const size_t boff1 = bbase + (size_t)(ci1 >> 2) * SEQ + (((ci1 & 3) ^ ((ci1 >> 3) & 3)) * 8);
  const int ldsb = w * 1024;

  f32x4 acc[4][4] = {};
#define DSTAGE(buf, kk)                                                  \
  do {                                                                   \
    async16((char*)Ab + (buf)*8192 + ldsb, vTw + aoff0 + (kk));          \
    async16((char*)Ab + (buf)*8192 + ldsb + 4096, vTw + aoff1 + (kk));   \
    async16((char*)Bb + (buf)*8192 + ldsb, kTw + boff0 + (kk));          \
    async16((char*)Bb + (buf)*8192 + ldsb + 4096, kTw + boff1 + (kk));   \
  } while (0)
  DSTAGE(0, 0);
  asm volatile("s_waitcnt vmcnt(0)" ::: "memory");
  __syncthreads();
  int cur = 0;
  for (int kk = 0; kk < 256; kk += 32) {
    if (kk + 32 < 256) DSTAGE(cur ^ 1, kk + 32);
    float wv[8];
#pragma unroll
    for (int e = 0; e < 8; ++e)
      wv[e] = exp2f(log2g * (float)(255 - (kk + hi * 8 + e)));
    bf16x8 af[4], bfr[4];
#pragma unroll
    for (int m = 0; m < 4; ++m) {
      bf16x8 a0 = *(const bf16x8*)&Ab[cur * 4096 + (wr * 64 + m * 16 + lr) * 32 + cs8];
#pragma unroll
      for (int e = 0; e < 8; ++e) a0[e] = (__bf16)((float)a0[e] * wv[e]);
      af[m] = a0;
    }
#pragma unroll
    for (int n = 0; n < 4; ++n)
      bfr[n] = *(const bf16x8*)&Bb[cur * 4096 + (wc * 64 + n * 16 + lr) * 32 + cs8];
#pragma unroll
    for (int m = 0; m < 4; ++m)
#pragma unroll
      for (int n = 0; n < 4; ++n)
        acc[m][n] = __builtin_amdgcn_mfma_f32_16x16x32_bf16(af[m], bfr[n],
                                                            acc[m][n], 0, 0, 0);
    asm volatile("s_waitcnt vmcnt(0)" ::: "memory");
    __syncthreads();
    cur ^= 1;
  }
#undef DSTAGE
  u16* scr = (w < 2) ? (Ab + w * 4096) : (Bb + (w - 2) * 4096);
#pragma unroll
  for (int m = 0; m < 4; ++m)
#pragma unroll
    for (int n = 0; n < 4; ++n)
#pragma unroll
      for (int r = 0; r < 4; ++r) {
        int row = m * 16 + (l >> 4) * 4 + r;
        int col = n * 16 + lr;
        scr[row * 64 + (((col >> 3) ^ (row & 7)) * 8) + (col & 7)] =
            f2bf(acc[m][n][r]);
      }
  u16* outb = dS + ((size_t)c * 16 + bh) * 65536;
#pragma unroll
  for (int p = 0; p < 8; ++p) {
    int row = (l >> 3) + p * 8;
    int ch = (l & 7) ^ (row & 7);
    bf16x8 v = *(bf16x8*)&scr[row * 64 + ch * 8];
    int colb = (l & 7) * 8;
    *(u16x8*)&outb[(size_t)(byv * 128 + wr * 64 + row) * 256 + bxk * 128 +
                   wc * 64 + colb] = *(u16x8*)&v;
  }
}

// ---------------- prefix scan over chunks (in place) -------------------------
__global__ __launch_bounds__(256) void k_scan(u16* __restrict__ dS) {
  const int bh = blockIdx.x >> 2, strip = blockIdx.x & 3;
  const int h = bh & 7;
  const float log2g = log2f(1.0f - exp2f(-5.0f - 4.0f * (float)h / 7.0f));
  const float gC = exp2f(256.0f * log2g);
  const int t = threadIdx.x;
  const int row = strip * 64 + (t >> 2), colg = (t & 3) * 64;
  float acc[64];
#pragma unroll
  for (int e = 0; e < 64; ++e) acc[e] = 0.f;
  for (int j = 0; j < 15; ++j) {
    size_t base = ((size_t)j * 16 + bh) * 65536 + (size_t)row * 256 + colg;
#pragma unroll
    for (int q8 = 0; q8 < 8; ++q8) {
      u16x8 v = *(const u16x8*)&dS[base + q8 * 8];
#pragma unroll
      for (int e = 0; e < 8; ++e) acc[q8 * 8 + e] = gC * acc[q8 * 8 + e] + bf2f(v[e]);
    }
#pragma unroll
    for (int q8 = 0; q8 < 8; ++q8) {
      u16x8 o8;
#pragma unroll
      for (int e = 0; e < 8; ++e) o8[e] = f2bf(acc[q8 * 8 + e]);
      *(u16x8*)&dS[base + q8 * 8] = o8;
    }
  }
}

// ---------------- chunked retention: cross (q.S) + intra (chunk-local) -------
__global__ __launch_bounds__(512) void k_attn2(const u16* __restrict__ qw,
                                               const u16* __restrict__ kw,
                                               const u16* __restrict__ vTw,
                                               const u16* __restrict__ S,
                                               u16* __restrict__ rtb) {
  __shared__ __align__(16) u16 k_lds[2][32 * 256];
  __shared__ __align__(16) u16 vT_lds[2][256 * 32];
  __shared__ __align__(16) u16 P_lds[128 * 32];
  const int qx = blockIdx.x, bh = blockIdx.y;
  const int b = bh >> 3, h = bh & 7;
  const int tid = threadIdx.x, l = tid & 63, w = tid >> 6;
  const int lr = l & 15, lk8 = (l >> 4) * 8;
  const int q0 = qx * 128;
  const int c = qx >> 1, chunk_base = c * 256;
  const float log2g = log2f(1.0f - exp2f(-5.0f - 4.0f * (float)h / 7.0f));
  const int cs_v8 = (((l >> 4) ^ ((lr >> 1) & 3)) * 8);
  const int lr7 = lr & 7;

  bf16x8 qf[8];
  {
    const u16* qbase = qw + ((size_t)bh * SEQ + q0 + w * 16 + lr) * HD + lk8;
#pragma unroll
    for (int kd = 0; kd < 8; ++kd) qf[kd] = *(const bf16x8*)(qbase + kd * 32);
  }
  const int ldsb = w * 1024;
  f32x4 o[16] = {};
  int cur = 0;

  // ---- cross phase: o += q . S_c^T ----
  if (c > 0) {
    const size_t sbase = ((size_t)(c - 1) * 16 + bh) * 65536;
    size_t soff[2];
#pragma unroll
    for (int j = 0; j < 2; ++j) {
      int ci = tid + 512 * j;
      soff[j] = sbase + (size_t)(ci >> 2) * 256 + (((ci & 3) ^ ((ci >> 3) & 3)) * 8);
    }
#define SSTAGE(buf, kk)                                                        \
    do {                                                                       \
      _Pragma("unroll") for (int j = 0; j < 2; ++j)                            \
        async16((char*)&vT_lds[buf][0] + ldsb + j * 8192, S + soff[j] + (kk)); \
    } while (0)
    SSTAGE(0, 0);
    asm volatile("s_waitcnt vmcnt(0)" ::: "memory");
    __syncthreads();
    cur = 0;
    for (int kd = 0; kd < 8; ++kd) {
      if (kd + 1 < 8) SSTAGE(cur ^ 1, (kd + 1) * 32);
#pragma unroll
      for (int fd = 0; fd < 16; ++fd) {
        bf16x8 sb = *(const bf16x8*)&vT_lds[cur][(fd * 16 + lr) * 32 + cs_v8];
        o[fd] = __builtin_amdgcn_mfma_f32_16x16x32_bf16(qf[kd], sb, o[fd], 0, 0, 0);
      }
      asm volatile("s_waitcnt vmcnt(0)" ::: "memory");
      __syncthreads();
      cur ^= 1;
    }
#undef SSTAGE
    float sc[4];
#pragma unroll
    for (int r = 0; r < 4; ++r) {
      int dlt = ((q0 + w * 16 + (l >> 4) * 4 + r) & 255) + 1;
      sc[r] = 0.0625f * exp2f(log2g * (float)dlt);
    }
#pragma unroll
    for (int fd = 0; fd < 16; ++fd)
#pragma unroll
      for (int r = 0; r < 4; ++r) o[fd][r] *= sc[r];
  }

  // ---- intra phase: chunk-local quadratic ----
  size_t koff[2], voff[2];
#pragma unroll
  for (int j = 0; j < 2; ++j) {
    int ci = tid + 512 * j;
    koff[j] = ((size_t)bh * SEQ + (ci >> 5)) * HD + (((ci & 31) ^ ((ci >> 5) & 7)) * 8);
    voff[j] = ((size_t)bh * HD + (ci >> 2)) * SEQ + (((ci & 3) ^ ((ci >> 3) & 3)) * 8);
  }
#define ASTAGE(buf, s0)                                                        \
  do {                                                                         \
    _Pragma("unroll") for (int j = 0; j < 2; ++j) {                            \
      async16((char*)&k_lds[buf][0] + ldsb + j * 8192,                         \
              kw + koff[j] + (size_t)(s0)*HD);                                 \
      async16((char*)&vT_lds[buf][0] + ldsb + j * 8192,                        \
              vTw + voff[j] + (size_t)(s0));                                   \
    }                                                                          \
  } while (0)
  const int nt = (q0 + 128 - chunk_base) / 32;
  ASTAGE(0, chunk_base);
  asm volatile("s_waitcnt vmcnt(0)" ::: "memory");
  __syncthreads();
  cur = 0;
  for (int t = 0; t < nt; ++t) {
    const int s0 = chunk_base + t * 32;
    if (t + 1 < nt) ASTAGE(cur ^ 1, s0 + 32);
    f32x4 sf[2] = {};
#pragma unroll
    for (int fc = 0; fc < 2; ++fc) {
      const int R = fc * 16 + lr;
#pragma unroll
      for (int kd = 0; kd < 8; ++kd) {
        bf16x8 kb = *(const bf16x8*)&k_lds[cur][R * 256 + (((kd * 4 + (l >> 4)) ^ lr7) * 8)];
        sf[fc] = __builtin_amdgcn_mfma_f32_16x16x32_bf16(qf[kd], kb, sf[fc], 0, 0, 0);
      }
    }
#pragma unroll
    for (int fc = 0; fc < 2; ++fc) {
      int s_l = fc * 16 + lr;
      int chunk = s_l >> 3;
#pragma unroll
      for (int r = 0; r < 4; ++r) {
        int n_l = w * 16 + (l >> 4) * 4 + r;
        int dist = (q0 + n_l) - (s0 + s_l);
        float p = 0.0f;
        if (dist >= 0) p = sf[fc][r] * 0.0625f * exp2f((float)dist * log2g);
        P_lds[n_l * 32 + ((chunk ^ ((n_l >> 1) & 3)) * 8) + (s_l & 7)] = f2bf(p);
      }
    }
    bf16x8 pa = *(const bf16x8*)&P_lds[(w * 16 + lr) * 32 + cs_v8];
#pragma unroll
    for (int fd = 0; fd < 16; ++fd) {
      bf16x8 vb = *(const bf16x8*)&vT_lds[cur][(fd * 16 + lr) * 32 + cs_v8];
      o[fd] = __builtin_amdgcn_mfma_f32_16x16x32_bf16(pa, vb, o[fd], 0, 0, 0);
    }
    asm volatile("s_waitcnt vmcnt(0)" ::: "memory");
    __syncthreads();
    cur ^= 1;
  }
#undef ASTAGE
  size_t trow = (size_t)b * SEQ + q0 + w * 16 + (l >> 4) * 4;
#pragma unroll
  for (int fd = 0; fd < 16; ++fd) {
    int cc = h * HD + fd * 16 + lr;
#pragma unroll
    for (int r = 0; r < 4; ++r)
      rtb[(trow + r) * HIDDEN + cc] = f2bf(o[fd][r]);
  }
}

// ---------------- groupnorm + silu gate (in-place on bf16 ret) ----------------
__global__ __launch_bounds__(256) void k_gate(u16* __restrict__ rg,
                                              const u16* __restrict__ gw,
                                              const float* __restrict__ gnw,
                                              const float* __restrict__ gnb) {
  int g = blockIdx.x * 4 + (threadIdx.x >> 6);
  int l = threadIdx.x & 63;
  int t = g >> 3, h = g & 7;
  size_t base = (size_t)t * HIDDEN + h * HD + l * 4;
  ushort4 r4 = *(const ushort4*)(rg + base);
  float rv[4] = {bf2f(r4.x), bf2f(r4.y), bf2f(r4.z), bf2f(r4.w)};
  float s = rv[0] + rv[1] + rv[2] + rv[3];
  float sq = rv[0] * rv[0] + rv[1] * rv[1] + rv[2] * rv[2] + rv[3] * rv[3];
#pragma unroll
  for (int off = 32; off > 0; off >>= 1) {
    s += __shfl_xor(s, off);
    sq += __shfl_xor(sq, off);
  }
  float mean = s * (1.0f / 256.0f);
  float var = sq * (1.0f / 256.0f) - mean * mean;
  float rstd = rsqrtf(var + 1e-5f);
  int cb = h * HD + l * 4;
  float4 wv = *(const float4*)(gnw + cb);
  float4 bv = *(const float4*)(gnb + cb);
  ushort4 gg = *(const ushort4*)(gw + base);
  float gf[4] = {bf2f(gg.x), bf2f(gg.y), bf2f(gg.z), bf2f(gg.w)};
  float wa[4] = {wv.x, wv.y, wv.z, wv.w};
  float ba[4] = {bv.x, bv.y, bv.z, bv.w};
  ushort4 ov;
  u16* po = (u16*)&ov;
#pragma unroll
  for (int e = 0; e < 4; ++e) {
    float nrm = (rv[e] - mean) * rstd * wa[e] + ba[e];
    float gv = gf[e];
    float si = gv / (1.0f + expf(-gv));
    po[e] = f2bf(si * nrm);
  }
  *(ushort4*)(rg + base) = ov;
}

extern "C" void kernel_launch(void* const* d_in, const int* in_sizes, int n_in,
                              void* d_out, int out_size, void* d_ws, size_t ws_size,
                              hipStream_t stream) {
  (void)in_sizes; (void)n_in; (void)out_size; (void)ws_size;
  const float* x   = (const float*)d_in[0];
  const float* w_q = (const float*)d_in[1];
  const float* b_q = (const float*)d_in[2];
  const float* w_k = (const float*)d_in[3];
  const float* b_k = (const float*)d_in[4];
  const float* w_v = (const float*)d_in[5];
  const float* b_v = (const float*)d_in[6];
  const float* w_g = (const float*)d_in[7];
  const float* b_g = (const float*)d_in[8];
  const float* w_o = (const float*)d_in[9];
  const float* b_o = (const float*)d_in[10];
  const float* gnw = (const float*)d_in[11];
  const float* gnb = (const float*)d_in[12];

  // workspace layout — peak 200 MiB, time-multiplexed:
  //  @0   (32M): xb -> kTw (after projections) -> rtg (after scan)
  //  @32M (32M): wT[q,k,v,g] -> dS/S (after projections); w_oT @64M stays
  //  @72M qw, @104M kw, @136M vTw, @168M gw
  char* ws = (char*)d_ws;
  u16* slot0 = (u16*)(ws);
  u16* wT    = (u16*)(ws + 33554432ULL);
  u16* dS    = (u16*)(ws + 33554432ULL);   // overlays wT[q..g] after projections
  u16* qw    = (u16*)(ws + 75497472ULL);
  u16* kw    = (u16*)(ws + 109051904ULL);
  u16* vTw   = (u16*)(ws + 142606336ULL);
  u16* gw    = (u16*)(ws + 176160768ULL);
  u16* xb    = slot0;
  u16* kTw   = slot0;
  u16* rtg   = slot0;

  const size_t WSZ = 4194304;  // elements per transposed weight matrix

  k_cvt_x<<<16384, 256, 0, stream>>>(x, xb);
  k_transpose<<<dim3(32, 32, 5), 256, 0, stream>>>(w_q, w_k, w_v, w_g, w_o, wT);
  k_gemm_q<<<dim3(16, 64), 256, 0, stream>>>(xb, wT,           b_q, qw);
  k_gemm_k<<<dim3(16, 64), 256, 0, stream>>>(xb, wT + WSZ,     b_k, kw);
  k_gemm_v<<<dim3(16, 64), 256, 0, stream>>>(xb, wT + 2 * WSZ, b_v, vTw);
  k_gemm_g<<<dim3(16, 64), 256, 0, stream>>>(xb, wT + 3 * WSZ, b_g, gw);
  k_transpose_k<<<dim3(4, 64, 16), 256, 0, stream>>>(kw, kTw);
  k_dstate<<<dim3(4, 16, 16), 256, 0, stream>>>(vTw, kTw, dS);
  k_scan<<<64, 256, 0, stream>>>(dS);
  k_attn2<<<dim3(32, 16), 512, 0, stream>>>(qw, kw, vTw, dS, rtg);
  k_gate<<<16384, 256, 0, stream>>>(rtg, gw, gnw, gnb);
  k_gemm_o<<<dim3(16, 64), 256, 0, stream>>>(rtg, wT + 4 * WSZ, b_o, (float*)d_out);
}

// Round 10
// 706.864 us; speedup vs baseline: 5.2187x; 1.0564x over previous
//
#include <hip/hip_runtime.h>

typedef unsigned short u16;
typedef unsigned int u32;
typedef __bf16 bf16x8 __attribute__((ext_vector_type(8)));
typedef unsigned short u16x8 __attribute__((ext_vector_type(8)));
typedef float f32x4 __attribute__((ext_vector_type(4)));

#define HIDDEN 2048
#define SEQ 4096
#define HEADS 8
#define HD 256

__device__ __forceinline__ u16 f2bf(float f) {
  u32 u = __float_as_uint(f);
  u32 r = (u + 0x7fffu + ((u >> 16) & 1u)) >> 16;
  return (u16)r;
}
__device__ __forceinline__ float bf2f(u16 h) {
  return __uint_as_float(((u32)h) << 16);
}
__device__ __forceinline__ void async16(void* lds, const void* g) {
  __builtin_amdgcn_global_load_lds(
      (__attribute__((address_space(1))) void*)g,
      (__attribute__((address_space(3))) void*)lds, 16, 0, 0);
}

// ---------------- convert x to bf16 ----------------
__global__ __launch_bounds__(256) void k_cvt_x(const float* __restrict__ x,
                                               u16* __restrict__ xb) {
  int i = blockIdx.x * 256 + threadIdx.x;
  float4 v = ((const float4*)x)[i];
  ushort4 o;
  o.x = f2bf(v.x); o.y = f2bf(v.y); o.z = f2bf(v.z); o.w = f2bf(v.w);
  ((ushort4*)xb)[i] = o;
}

// ---------------- transpose weights to bf16 W^T[c][k] ----------------
__global__ __launch_bounds__(256) void k_transpose(
    const float* __restrict__ w0, const float* __restrict__ w1,
    const float* __restrict__ w2, const float* __restrict__ w3,
    const float* __restrict__ w4, u16* __restrict__ dst) {
  const float* src = (blockIdx.z == 0) ? w0 : (blockIdx.z == 1) ? w1
                   : (blockIdx.z == 2) ? w2 : (blockIdx.z == 3) ? w3 : w4;
  u16* out = dst + (size_t)blockIdx.z * HIDDEN * HIDDEN;
  __shared__ float tile[64 * 65];
  int k0 = blockIdx.y * 64, c0 = blockIdx.x * 64;
  int tid = threadIdx.x;
#pragma unroll
  for (int j = 0; j < 16; ++j) {
    int f = j * 256 + tid;
    int r = f >> 6, c = f & 63;
    tile[r * 65 + c] = src[(size_t)(k0 + r) * HIDDEN + c0 + c];
  }
  __syncthreads();
#pragma unroll
  for (int j = 0; j < 16; ++j) {
    int f = j * 256 + tid;
    int cc = f >> 6, kk = f & 63;
    out[(size_t)(c0 + cc) * HIDDEN + k0 + kk] = f2bf(tile[kk * 65 + cc]);
  }
}

// ---------------- bf16 transpose: kw [bh][n][d] -> kTw [bh][d][n] ------------
__global__ __launch_bounds__(256) void k_transpose_k(const u16* __restrict__ kw,
                                                     u16* __restrict__ kTw) {
  __shared__ u16 tile[64][65];
  const int d0 = blockIdx.x * 64, n0 = blockIdx.y * 64;
  const int bh = blockIdx.z;
  const u16* src = kw + (size_t)bh * SEQ * HD;
  u16* dst = kTw + (size_t)bh * HD * SEQ;
  const int tid = threadIdx.x;
#pragma unroll
  for (int j = 0; j < 4; ++j) {
    int f = j * 256 + tid;
    int r = f >> 4, c4 = (f & 15) * 4;
    ushort4 v = *(const ushort4*)&src[(size_t)(n0 + r) * HD + d0 + c4];
    tile[r][c4] = v.x; tile[r][c4 + 1] = v.y;
    tile[r][c4 + 2] = v.z; tile[r][c4 + 3] = v.w;
  }
  __syncthreads();
#pragma unroll
  for (int j = 0; j < 4; ++j) {
    int f = j * 256 + tid;
    int dr = f >> 4, n4 = (f & 15) * 4;
    ushort4 o;
    o.x = tile[n4][dr]; o.y = tile[n4 + 1][dr];
    o.z = tile[n4 + 2][dr]; o.w = tile[n4 + 3][dr];
    *(ushort4*)&dst[(size_t)(d0 + dr) * SEQ + n0 + n4] = o;
  }
}

// ---------------- 128x128 GEMM body, counted-vmcnt pipeline ------------------
// Per K-step: STAGE(next); vmcnt(4) [keep next's 4 loads in flight]; barrier;
// ds_read+MFMA; barrier. Last step: vmcnt(0). FIFO order guarantees the 4
// newest outstanding loads are next-buffer's.
template <int MODE>
__device__ __forceinline__ void gemm_body(const u16* __restrict__ A,
                                          const u16* __restrict__ Bt,
                                          const float* __restrict__ bias,
                                          void* __restrict__ out,
                                          int bx, int by, u16* Ab, u16* Bb) {
  const int tid = threadIdx.x;
  const int l = tid & 63, w = tid >> 6;
  const int wr = w >> 1, wc = w & 1;
  const int t0 = by * 128, c0 = bx * 128;
  const int lr = l & 15;
  const int cs8 = (((l >> 4) ^ ((lr >> 1) & 3)) * 8);
  const int ci0 = tid, ci1 = tid + 256;
  const size_t aoff0 = (size_t)(t0 + (ci0 >> 2)) * HIDDEN + (((ci0 & 3) ^ ((ci0 >> 3) & 3)) * 8);
  const size_t aoff1 = (size_t)(t0 + (ci1 >> 2)) * HIDDEN + (((ci1 & 3) ^ ((ci1 >> 3) & 3)) * 8);
  const size_t boff0 = (size_t)(c0 + (ci0 >> 2)) * HIDDEN + (((ci0 & 3) ^ ((ci0 >> 3) & 3)) * 8);
  const size_t boff1 = (size_t)(c0 + (ci1 >> 2)) * HIDDEN + (((ci1 & 3) ^ ((ci1 >> 3) & 3)) * 8);
  const int ldsb = w * 1024;

  f32x4 acc[4][4] = {};
#define GSTAGE(buf, kk)                                                  \
  do {                                                                   \
    async16((char*)Ab + (buf)*8192 + ldsb, A + aoff0 + (kk));            \
    async16((char*)Ab + (buf)*8192 + ldsb + 4096, A + aoff1 + (kk));     \
    async16((char*)Bb + (buf)*8192 + ldsb, Bt + boff0 + (kk));           \
    async16((char*)Bb + (buf)*8192 + ldsb + 4096, Bt + boff1 + (kk));    \
  } while (0)

  GSTAGE(0, 0);
  int cur = 0;
  for (int kk = 0; kk < HIDDEN; kk += 32) {
    if (kk + 32 < HIDDEN) {
      GSTAGE(cur ^ 1, kk + 32);
      asm volatile("s_waitcnt vmcnt(4)" ::: "memory");
    } else {
      asm volatile("s_waitcnt vmcnt(0)" ::: "memory");
    }
    __syncthreads();
    bf16x8 af[4], bfr[4];
#pragma unroll
    for (int m = 0; m < 4; ++m)
      af[m] = *(const bf16x8*)&Ab[cur * 4096 + (wr * 64 + m * 16 + lr) * 32 + cs8];
#pragma unroll
    for (int n = 0; n < 4; ++n)
      bfr[n] = *(const bf16x8*)&Bb[cur * 4096 + (wc * 64 + n * 16 + lr) * 32 + cs8];
#pragma unroll
    for (int m = 0; m < 4; ++m)
#pragma unroll
      for (int n = 0; n < 4; ++n)
        acc[m][n] = __builtin_amdgcn_mfma_f32_16x16x32_bf16(af[m], bfr[n],
                                                            acc[m][n], 0, 0, 0);
    __syncthreads();
    cur ^= 1;
  }
#undef GSTAGE
  if constexpr (MODE == 3) {
    float* scf = (float*)Ab + w * 1024;
    for (int m = 0; m < 4; ++m) {
#pragma unroll
      for (int n = 0; n < 4; ++n) {
        int cl = c0 + wc * 64 + n * 16 + lr;
        float bi = bias[cl];
        int unit = n * 4 + (lr >> 2);
#pragma unroll
        for (int r = 0; r < 4; ++r) {
          int row = (l >> 4) * 4 + r;
          scf[row * 64 + ((unit ^ row) & 15) * 4 + (lr & 3)] = acc[m][n][r] + bi;
        }
      }
#pragma unroll
      for (int p = 0; p < 4; ++p) {
        int row = (l >> 4) + p * 4;
        int unit = l & 15;
        f32x4 v4 = *(f32x4*)&scf[row * 64 + ((unit ^ row) & 15) * 4];
        int tl = t0 + wr * 64 + m * 16 + row;
        *(f32x4*)&((float*)out)[(size_t)tl * HIDDEN + c0 + wc * 64 + unit * 4] = v4;
      }
    }
  } else {
    u16* scr = (w < 2) ? (Ab + w * 4096) : (Bb + (w - 2) * 4096);
#pragma unroll
    for (int m = 0; m < 4; ++m)
#pragma unroll
      for (int n = 0; n < 4; ++n) {
        int cl = c0 + wc * 64 + n * 16 + lr;
        float bi = bias[cl];
#pragma unroll
        for (int r = 0; r < 4; ++r) {
          int trow = m * 16 + (l >> 4) * 4 + r;
          int tcol = n * 16 + lr;
          int row = (MODE == 1) ? tcol : trow;
          int col = (MODE == 1) ? trow : tcol;
          scr[row * 64 + (((col >> 3) ^ (row & 7)) * 8) + (col & 7)] =
              f2bf(acc[m][n][r] + bi);
        }
      }
#pragma unroll
    for (int p = 0; p < 8; ++p) {
      int row = (l >> 3) + p * 8;
      int ch = (l & 7) ^ (row & 7);
      bf16x8 v = *(bf16x8*)&scr[row * 64 + ch * 8];
      int colb = (l & 7) * 8;
      if constexpr (MODE == 0) {
        int tl = t0 + wr * 64 + row;
        int cb = c0 + wc * 64 + colb;
        int d = cb & 255, hh = cb >> 8;
        int ntok = tl & (SEQ - 1), bb = tl >> 12;
        u16x8 ov;
#pragma unroll
        for (int jp = 0; jp < 4; ++jp) {
          float theta = exp2f(-(float)((d >> 1) + jp) * 0.1046276623f);
          float sv, cv;
          sincosf((float)ntok * theta, &sv, &cv);
          float e = (float)v[2 * jp], o = (float)v[2 * jp + 1];
          ov[2 * jp] = f2bf(e * cv - o * sv);
          ov[2 * jp + 1] = f2bf(o * cv + e * sv);
        }
        *(u16x8*)&((u16*)out)[((size_t)(bb * HEADS + hh) * SEQ + ntok) * HD + d] = ov;
      } else if constexpr (MODE == 1) {
        int dfull = c0 + wc * 64 + row;
        int d = dfull & 255, hh = dfull >> 8;
        int ntg = t0 + wr * 64 + colb;
        int nb = ntg & (SEQ - 1), bb = ntg >> 12;
        *(u16x8*)&((u16*)out)[((size_t)(bb * HEADS + hh) * HD + d) * SEQ + nb] =
            *(u16x8*)&v;
      } else {
        int tl = t0 + wr * 64 + row;
        *(u16x8*)&((u16*)out)[(size_t)tl * HIDDEN + c0 + wc * 64 + colb] =
            *(u16x8*)&v;
      }
    }
  }
}

#define GEMM_KERNEL(NAME, MODE, OUTT)                                         \
  __global__ __launch_bounds__(256) void NAME(                                \
      const u16* __restrict__ A, const u16* __restrict__ Bt,                  \
      const float* __restrict__ bias, OUTT* __restrict__ out) {               \
    __shared__ __align__(16) u16 Ab[8192];                                    \
    __shared__ __align__(16) u16 Bb[8192];                                    \
    gemm_body<MODE>(A, Bt, bias, (void*)out, blockIdx.x, blockIdx.y, Ab, Bb); \
  }

GEMM_KERNEL(k_gemm_q, 0, u16)
GEMM_KERNEL(k_gemm_k, 0, u16)
GEMM_KERNEL(k_gemm_v, 1, u16)
GEMM_KERNEL(k_gemm_g, 2, u16)
GEMM_KERNEL(k_gemm_o, 3, float)

// ---------------- chunk state build: dS_T[c][bh][d_v][d_k] (C=256) ----------
__global__ __launch_bounds__(256) void k_dstate(const u16* __restrict__ vTw,
                                                const u16* __restrict__ kTw,
                                                u16* __restrict__ dS) {
  __shared__ __align__(16) u16 Ab[2 * 4096];
  __shared__ __align__(16) u16 Bb[2 * 4096];
  const int byv = blockIdx.x >> 1, bxk = blockIdx.x & 1;
  const int c = blockIdx.y, bh = blockIdx.z;
  const int h = bh & 7;
  const float log2g = log2f(1.0f - exp2f(-5.0f - 4.0f * (float)h / 7.0f));
  const int tid = threadIdx.x, l = tid & 63, w = tid >> 6;
  const int wr = w >> 1, wc = w & 1;
  const int lr = l & 15, hi = l >> 4;
  const int cs8 = ((hi ^ ((lr >> 1) & 3)) * 8);
  const int ci0 = tid, ci1 = tid + 256;
  const size_t abase = ((size_t)bh * HD + byv * 128) * SEQ + (size_t)c * 256;
  const size_t bbase = ((size_t)bh * HD + bxk * 128) * SEQ + (size_t)c * 256;
  const size_t aoff0 = abase + (size_t)(ci0 >> 2) * SEQ + (((ci0 & 3) ^ ((ci0 >> 3) & 3)) * 8);
  const size_t aoff1 = abase + (size_t)(ci1 >> 2) * SEQ + (((ci1 & 3) ^ ((ci1 >> 3) & 3)) * 8);
  const size_t boff0 = bbase + (size_t)(ci0 >> 2) * SEQ + (((ci0 & 3) ^ ((ci0 >> 3) & 3)) * 8);
  const size_t boff1 = bbase + (size_t)(ci1 >> 2) * SEQ + (((ci1 & 3) ^ ((ci1 >> 3) & 3)) * 8);
  const int ldsb = w * 1024;

  f32x4 acc[4][4] = {};
#define DSTAGE(buf, kk)                                                  \
  do {                                                                   \
    async16((char*)Ab + (buf)*8192 + ldsb, vTw + aoff0 + (kk));          \
    async16((char*)Ab + (buf)*8192 + ldsb + 4096, vTw + aoff1 + (kk));   \
    async16((char*)Bb + (buf)*8192 + ldsb, kTw + boff0 + (kk));          \
    async16((char*)Bb + (buf)*8192 + ldsb + 4096, kTw + boff1 + (kk));   \
  } while (0)
  DSTAGE(0, 0);
  asm volatile("s_waitcnt vmcnt(0)" ::: "memory");
  __syncthreads();
  int cur = 0;
  for (int kk = 0; kk < 256; kk += 32) {
    if (kk + 32 < 256) DSTAGE(cur ^ 1, kk + 32);
    float wv[8];
#pragma unroll
    for (int e = 0; e < 8; ++e)
      wv[e] = exp2f(log2g * (float)(255 - (kk + hi * 8 + e)));
    bf16x8 af[4], bfr[4];
#pragma unroll
    for (int m = 0; m < 4; ++m) {
      bf16x8 a0 = *(const bf16x8*)&Ab[cur * 4096 + (wr * 64 + m * 16 + lr) * 32 + cs8];
#pragma unroll
      for (int e = 0; e < 8; ++e) a0[e] = (__bf16)((float)a0[e] * wv[e]);
      af[m] = a0;
    }
#pragma unroll
    for (int n = 0; n < 4; ++n)
      bfr[n] = *(const bf16x8*)&Bb[cur * 4096 + (wc * 64 + n * 16 + lr) * 32 + cs8];
#pragma unroll
    for (int m = 0; m < 4; ++m)
#pragma unroll
      for (int n = 0; n < 4; ++n)
        acc[m][n] = __builtin_amdgcn_mfma_f32_16x16x32_bf16(af[m], bfr[n],
                                                            acc[m][n], 0, 0, 0);
    asm volatile("s_waitcnt vmcnt(0)" ::: "memory");
    __syncthreads();
    cur ^= 1;
  }
#undef DSTAGE
  u16* scr = (w < 2) ? (Ab + w * 4096) : (Bb + (w - 2) * 4096);
#pragma unroll
  for (int m = 0; m < 4; ++m)
#pragma unroll
    for (int n = 0; n < 4; ++n)
#pragma unroll
      for (int r = 0; r < 4; ++r) {
        int row = m * 16 + (l >> 4) * 4 + r;
        int col = n * 16 + lr;
        scr[row * 64 + (((col >> 3) ^ (row & 7)) * 8) + (col & 7)] =
            f2bf(acc[m][n][r]);
      }
  u16* outb = dS + ((size_t)c * 16 + bh) * 65536;
#pragma unroll
  for (int p = 0; p < 8; ++p) {
    int row = (l >> 3) + p * 8;
    int ch = (l & 7) ^ (row & 7);
    bf16x8 v = *(bf16x8*)&scr[row * 64 + ch * 8];
    int colb = (l & 7) * 8;
    *(u16x8*)&outb[(size_t)(byv * 128 + wr * 64 + row) * 256 + bxk * 128 +
                   wc * 64 + colb] = *(u16x8*)&v;
  }
}

// ---------------- prefix scan over chunks (in place, 256 blocks) -------------
__global__ __launch_bounds__(256) void k_scan(u16* __restrict__ dS) {
  const int bh = blockIdx.x >> 4, strip = blockIdx.x & 15;
  const int h = bh & 7;
  const float log2g = log2f(1.0f - exp2f(-5.0f - 4.0f * (float)h / 7.0f));
  const float gC = exp2f(256.0f * log2g);
  const int t = threadIdx.x;
  const int row = strip * 16 + (t >> 4), colg = (t & 15) * 16;
  float acc[16];
#pragma unroll
  for (int e = 0; e < 16; ++e) acc[e] = 0.f;
  for (int j = 0; j < 15; ++j) {
    size_t base = ((size_t)j * 16 + bh) * 65536 + (size_t)row * 256 + colg;
#pragma unroll
    for (int q8 = 0; q8 < 2; ++q8) {
      u16x8 v = *(const u16x8*)&dS[base + q8 * 8];
#pragma unroll
      for (int e = 0; e < 8; ++e) acc[q8 * 8 + e] = gC * acc[q8 * 8 + e] + bf2f(v[e]);
    }
#pragma unroll
    for (int q8 = 0; q8 < 2; ++q8) {
      u16x8 o8;
#pragma unroll
      for (int e = 0; e < 8; ++e) o8[e] = f2bf(acc[q8 * 8 + e]);
      *(u16x8*)&dS[base + q8 * 8] = o8;
    }
  }
}

// ---------------- chunked retention: cross (q.S) + intra (chunk-local) -------
__global__ __launch_bounds__(512) void k_attn2(const u16* __restrict__ qw,
                                               const u16* __restrict__ kw,
                                               const u16* __restrict__ vTw,
                                               const u16* __restrict__ S,
                                               u16* __restrict__ rtb) {
  __shared__ __align__(16) u16 k_lds[2][32 * 256];
  __shared__ __align__(16) u16 vT_lds[2][256 * 32];
  __shared__ __align__(16) u16 P_lds[128 * 32];
  const int qx = blockIdx.x, bh = blockIdx.y;
  const int b = bh >> 3, h = bh & 7;
  const int tid = threadIdx.x, l = tid & 63, w = tid >> 6;
  const int lr = l & 15, lk8 = (l >> 4) * 8;
  const int q0 = qx * 128;
  const int c = qx >> 1, chunk_base = c * 256;
  const float log2g = log2f(1.0f - exp2f(-5.0f - 4.0f * (float)h / 7.0f));
  const int cs_v8 = (((l >> 4) ^ ((lr >> 1) & 3)) * 8);
  const int lr7 = lr & 7;

  bf16x8 qf[8];
  {
    const u16* qbase = qw + ((size_t)bh * SEQ + q0 + w * 16 + lr) * HD + lk8;
#pragma unroll
    for (int kd = 0; kd < 8; ++kd) qf[kd] = *(const bf16x8*)(qbase + kd * 32);
  }
  const int ldsb = w * 1024;
  f32x4 o[16] = {};
  int cur = 0;

  // ---- cross phase: o += q . S_c^T ----
  if (c > 0) {
    const size_t sbase = ((size_t)(c - 1) * 16 + bh) * 65536;
    size_t soff[2];
#pragma unroll
    for (int j = 0; j < 2; ++j) {
      int ci = tid + 512 * j;
      soff[j] = sbase + (size_t)(ci >> 2) * 256 + (((ci & 3) ^ ((ci >> 3) & 3)) * 8);
    }
#define SSTAGE(buf, kk)                                                        \
    do {                                                                       \
      _Pragma("unroll") for (int j = 0; j < 2; ++j)                            \
        async16((char*)&vT_lds[buf][0] + ldsb + j * 8192, S + soff[j] + (kk)); \
    } while (0)
    SSTAGE(0, 0);
    asm volatile("s_waitcnt vmcnt(0)" ::: "memory");
    __syncthreads();
    cur = 0;
    for (int kd = 0; kd < 8; ++kd) {
      if (kd + 1 < 8) SSTAGE(cur ^ 1, (kd + 1) * 32);
#pragma unroll
      for (int fd = 0; fd < 16; ++fd) {
        bf16x8 sb = *(const bf16x8*)&vT_lds[cur][(fd * 16 + lr) * 32 + cs_v8];
        o[fd] = __builtin_amdgcn_mfma_f32_16x16x32_bf16(qf[kd], sb, o[fd], 0, 0, 0);
      }
      asm volatile("s_waitcnt vmcnt(0)" ::: "memory");
      __syncthreads();
      cur ^= 1;
    }
#undef SSTAGE
    float sc[4];
#pragma unroll
    for (int r = 0; r < 4; ++r) {
      int dlt = ((q0 + w * 16 + (l >> 4) * 4 + r) & 255) + 1;
      sc[r] = 0.0625f * exp2f(log2g * (float)dlt);
    }
#pragma unroll
    for (int fd = 0; fd < 16; ++fd)
#pragma unroll
      for (int r = 0; r < 4; ++r) o[fd][r] *= sc[r];
  }

  // ---- intra phase: chunk-local quadratic ----
  size_t koff[2], voff[2];
#pragma unroll
  for (int j = 0; j < 2; ++j) {
    int ci = tid + 512 * j;
    koff[j] = ((size_t)bh * SEQ + (ci >> 5)) * HD + (((ci & 31) ^ ((ci >> 5) & 7)) * 8);
    voff[j] = ((size_t)bh * HD + (ci >> 2)) * SEQ + (((ci & 3) ^ ((ci >> 3) & 3)) * 8);
  }
#define ASTAGE(buf, s0)                                                        \
  do {                                                                         \
    _Pragma("unroll") for (int j = 0; j < 2; ++j) {                            \
      async16((char*)&k_lds[buf][0] + ldsb + j * 8192,                         \
              kw + koff[j] + (size_t)(s0)*HD);                                 \
      async16((char*)&vT_lds[buf][0] + ldsb + j * 8192,                        \
              vTw + voff[j] + (size_t)(s0));                                   \
    }                                                                          \
  } while (0)
  const int nt = (q0 + 128 - chunk_base) / 32;
  ASTAGE(0, chunk_base);
  asm volatile("s_waitcnt vmcnt(0)" ::: "memory");
  __syncthreads();
  cur = 0;
  for (int t = 0; t < nt; ++t) {
    const int s0 = chunk_base + t * 32;
    if (t + 1 < nt) ASTAGE(cur ^ 1, s0 + 32);
    f32x4 sf[2] = {};
#pragma unroll
    for (int fc = 0; fc < 2; ++fc) {
      const int R = fc * 16 + lr;
#pragma unroll
      for (int kd = 0; kd < 8; ++kd) {
        bf16x8 kb = *(const bf16x8*)&k_lds[cur][R * 256 + (((kd * 4 + (l >> 4)) ^ lr7) * 8)];
        sf[fc] = __builtin_amdgcn_mfma_f32_16x16x32_bf16(qf[kd], kb, sf[fc], 0, 0, 0);
      }
    }
#pragma unroll
    for (int fc = 0; fc < 2; ++fc) {
      int s_l = fc * 16 + lr;
      int chunk = s_l >> 3;
#pragma unroll
      for (int r = 0; r < 4; ++r) {
        int n_l = w * 16 + (l >> 4) * 4 + r;
        int dist = (q0 + n_l) - (s0 + s_l);
        float p = 0.0f;
        if (dist >= 0) p = sf[fc][r] * 0.0625f * exp2f((float)dist * log2g);
        P_lds[n_l * 32 + ((chunk ^ ((n_l >> 1) & 3)) * 8) + (s_l & 7)] = f2bf(p);
      }
    }
    bf16x8 pa = *(const bf16x8*)&P_lds[(w * 16 + lr) * 32 + cs_v8];
#pragma unroll
    for (int fd = 0; fd < 16; ++fd) {
      bf16x8 vb = *(const bf16x8*)&vT_lds[cur][(fd * 16 + lr) * 32 + cs_v8];
      o[fd] = __builtin_amdgcn_mfma_f32_16x16x32_bf16(pa, vb, o[fd], 0, 0, 0);
    }
    asm volatile("s_waitcnt vmcnt(0)" ::: "memory");
    __syncthreads();
    cur ^= 1;
  }
#undef ASTAGE
  size_t trow = (size_t)b * SEQ + q0 + w * 16 + (l >> 4) * 4;
#pragma unroll
  for (int fd = 0; fd < 16; ++fd) {
    int cc = h * HD + fd * 16 + lr;
#pragma unroll
    for (int r = 0; r < 4; ++r)
      rtb[(trow + r) * HIDDEN + cc] = f2bf(o[fd][r]);
  }
}

// ---------------- groupnorm + silu gate (in-place on bf16 ret) ----------------
__global__ __launch_bounds__(256) void k_gate(u16* __restrict__ rg,
                                              const u16* __restrict__ gw,
                                              const float* __restrict__ gnw,
                                              const float* __restrict__ gnb) {
  int g = blockIdx.x * 4 + (threadIdx.x >> 6);
  int l = threadIdx.x & 63;
  int t = g >> 3, h = g & 7;
  size_t base = (size_t)t * HIDDEN + h * HD + l * 4;
  ushort4 r4 = *(const ushort4*)(rg + base);
  float rv[4] = {bf2f(r4.x), bf2f(r4.y), bf2f(r4.z), bf2f(r4.w)};
  float s = rv[0] + rv[1] + rv[2] + rv[3];
  float sq = rv[0] * rv[0] + rv[1] * rv[1] + rv[2] * rv[2] + rv[3] * rv[3];
#pragma unroll
  for (int off = 32; off > 0; off >>= 1) {
    s += __shfl_xor(s, off);
    sq += __shfl_xor(sq, off);
  }
  float mean = s * (1.0f / 256.0f);
  float var = sq * (1.0f / 256.0f) - mean * mean;
  float rstd = rsqrtf(var + 1e-5f);
  int cb = h * HD + l * 4;
  float4 wv = *(const float4*)(gnw + cb);
  float4 bv = *(const float4*)(gnb + cb);
  ushort4 gg = *(const ushort4*)(gw + base);
  float gf[4] = {bf2f(gg.x), bf2f(gg.y), bf2f(gg.z), bf2f(gg.w)};
  float wa[4] = {wv.x, wv.y, wv.z, wv.w};
  float ba[4] = {bv.x, bv.y, bv.z, bv.w};
  ushort4 ov;
  u16* po = (u16*)&ov;
#pragma unroll
  for (int e = 0; e < 4; ++e) {
    float nrm = (rv[e] - mean) * rstd * wa[e] + ba[e];
    float gv = gf[e];
    float si = gv / (1.0f + expf(-gv));
    po[e] = f2bf(si * nrm);
  }
  *(ushort4*)(rg + base) = ov;
}

extern "C" void kernel_launch(void* const* d_in, const int* in_sizes, int n_in,
                              void* d_out, int out_size, void* d_ws, size_t ws_size,
                              hipStream_t stream) {
  (void)in_sizes; (void)n_in; (void)out_size; (void)ws_size;
  const float* x   = (const float*)d_in[0];
  const float* w_q = (const float*)d_in[1];
  const float* b_q = (const float*)d_in[2];
  const float* w_k = (const float*)d_in[3];
  const float* b_k = (const float*)d_in[4];
  const float* w_v = (const float*)d_in[5];
  const float* b_v = (const float*)d_in[6];
  const float* w_g = (const float*)d_in[7];
  const float* b_g = (const float*)d_in[8];
  const float* w_o = (const float*)d_in[9];
  const float* b_o = (const float*)d_in[10];
  const float* gnw = (const float*)d_in[11];
  const float* gnb = (const float*)d_in[12];

  // workspace layout — peak 200 MiB, time-multiplexed:
  //  @0   (32M): xb -> kTw (after projections) -> rtg (after scan)
  //  @32M (32M): wT[q,k,v,g] -> dS/S (after projections); w_oT @64M stays
  //  @72M qw, @104M kw, @136M vTw, @168M gw
  char* ws = (char*)d_ws;
  u16* slot0 = (u16*)(ws);
  u16* wT    = (u16*)(ws + 33554432ULL);
  u16* dS    = (u16*)(ws + 33554432ULL);   // overlays wT[q..g] after projections
  u16* qw    = (u16*)(ws + 75497472ULL);
  u16* kw    = (u16*)(ws + 109051904ULL);
  u16* vTw   = (u16*)(ws + 142606336ULL);
  u16* gw    = (u16*)(ws + 176160768ULL);
  u16* xb    = slot0;
  u16* kTw   = slot0;
  u16* rtg   = slot0;

  const size_t WSZ = 4194304;  // elements per transposed weight matrix

  k_cvt_x<<<16384, 256, 0, stream>>>(x, xb);
  k_transpose<<<dim3(32, 32, 5), 256, 0, stream>>>(w_q, w_k, w_v, w_g, w_o, wT);
  k_gemm_q<<<dim3(16, 64), 256, 0, stream>>>(xb, wT,           b_q, qw);
  k_gemm_k<<<dim3(16, 64), 256, 0, stream>>>(xb, wT + WSZ,     b_k, kw);
  k_gemm_v<<<dim3(16, 64), 256, 0, stream>>>(xb, wT + 2 * WSZ, b_v, vTw);
  k_gemm_g<<<dim3(16, 64), 256, 0, stream>>>(xb, wT + 3 * WSZ, b_g, gw);
  k_transpose_k<<<dim3(4, 64, 16), 256, 0, stream>>>(kw, kTw);
  k_dstate<<<dim3(4, 16, 16), 256, 0, stream>>>(vTw, kTw, dS);
  k_scan<<<256, 256, 0, stream>>>(dS);
  k_attn2<<<dim3(32, 16), 512, 0, stream>>>(qw, kw, vTw, dS, rtg);
  k_gate<<<16384, 256, 0, stream>>>(rtg, gw, gnw, gnb);
  k_gemm_o<<<dim3(16, 64), 256, 0, stream>>>(rtg, wT + 4 * WSZ, b_o, (float*)d_out);
}